// Round 1
// baseline (990.262 us; speedup 1.0000x reference)
//
#include <hip/hip_runtime.h>
#include <stdint.h>

#define DM   768
#define HEADS 12
#define DK    64
#define SEQ  2048
#define BATCH  4

typedef __bf16 bf16_t;
typedef __bf16 bf16x8 __attribute__((ext_vector_type(8)));
typedef __bf16 bf16x4 __attribute__((ext_vector_type(4)));
typedef float  f32x4  __attribute__((ext_vector_type(4)));

// ---- workspace layout (bytes), all 256-aligned ----
#define OFF_FLAG 0
#define OFF_MASK 256
#define SZ_MASK  (BATCH*SEQ*(SEQ/32)*4)          // 2 MB packed mask bits
#define OFF_WT   (OFF_MASK + SZ_MASK)
#define SZ_WT1   (DM*DM*2)                       // one bf16 weight (transposed)
#define OFF_QP   (OFF_WT + 4*SZ_WT1)
#define SZ_PROJ  (BATCH*HEADS*SEQ*DK*2)          // 12.6 MB
#define OFF_KP   (OFF_QP + SZ_PROJ)
#define OFF_VT   (OFF_KP + SZ_PROJ)
#define OFF_CTX  (OFF_VT + SZ_PROJ)
// total ~57 MB

// Detect mask element width: int32 0/1 values have bytes 1,2,3 zero.
__global__ void detect_mask_kernel(const unsigned char* __restrict__ m, int* flag) {
    int u = threadIdx.x;  // 64 threads
    int any = m[4*u+1] | m[4*u+2] | m[4*u+3];
    unsigned long long b = __ballot(any != 0);
    if (u == 0) *flag = (b == 0ULL) ? 1 : 0;   // 1 => int32 layout, 0 => byte layout
}

// Pack mask (True => masked) into bits: word[e>>5] bit (e&31).
__global__ void pack_mask_kernel(const void* __restrict__ mraw, const int* __restrict__ flag,
                                 unsigned int* __restrict__ words) {
    const unsigned int total = BATCH*SEQ*SEQ;
    const int is32 = *flag;
    const int* mi = (const int*)mraw;
    const unsigned char* mb = (const unsigned char*)mraw;
    unsigned int stride = gridDim.x * blockDim.x;
    unsigned int lane = threadIdx.x & 63u;
    for (unsigned int e = blockIdx.x * blockDim.x + threadIdx.x; e < total; e += stride) {
        int v = is32 ? (mi[e] != 0) : (mb[e] != 0);
        unsigned long long bal = __ballot(v);
        if ((lane & 31u) == 0u)
            words[e >> 5] = (unsigned int)(bal >> ((lane >> 5) * 32u));
    }
}

// Transpose + convert weights to bf16: W[k][n] f32 -> Wt[n][k] bf16
__global__ void wt_cvt_kernel(const float* __restrict__ W0, const float* __restrict__ W1,
                              const float* __restrict__ W2, const float* __restrict__ W3,
                              bf16_t* __restrict__ dst) {
    const float* W = blockIdx.z == 0 ? W0 : blockIdx.z == 1 ? W1 : blockIdx.z == 2 ? W2 : W3;
    bf16_t* out = dst + (size_t)blockIdx.z * DM * DM;
    __shared__ float tile[64][65];
    int w = threadIdx.x >> 6, u = threadIdx.x & 63;
    int kb = blockIdx.x * 64, nb = blockIdx.y * 64;
    #pragma unroll
    for (int i = 0; i < 16; i++)
        tile[w + 4*i][u] = W[(size_t)(kb + w + 4*i)*DM + nb + u];
    __syncthreads();
    #pragma unroll
    for (int i = 0; i < 16; i++)
        out[(size_t)(nb + w + 4*i)*DM + kb + u] = (bf16_t)tile[u][w + 4*i];
}

// QKV projection GEMM: [8192x768] @ [768x768] -> q/k bf16 [b][h][s][d], v transposed [b][h][d][s]
__global__ __launch_bounds__(256) void proj_gemm_kernel(
        const float* __restrict__ Q, const float* __restrict__ K, const float* __restrict__ V,
        const float* __restrict__ bQ, const float* __restrict__ bK, const float* __restrict__ bV,
        const bf16_t* __restrict__ WT, bf16_t* __restrict__ QP, bf16_t* __restrict__ KP,
        bf16_t* __restrict__ VT) {
    const int z = blockIdx.z;
    const float* X   = z == 0 ? Q : z == 1 ? K : V;
    const float* bia = z == 0 ? bQ : z == 1 ? bK : bV;
    const bf16_t* Wt = WT + (size_t)z * DM * DM;
    int tid = threadIdx.x;
    int w = tid >> 6, u = tid & 63, c = u & 15, g = u >> 4;
    int rbase = blockIdx.x * 64 + w * 16;
    int nbase = blockIdx.y * 64;
    f32x4 zero = {0.f, 0.f, 0.f, 0.f};
    f32x4 acc[4] = {zero, zero, zero, zero};
    const float* arow = X + (size_t)(rbase + c) * DM;
    for (int k0 = 0; k0 < DM; k0 += 32) {
        const float4 a0 = *(const float4*)(arow + k0 + g*8);
        const float4 a1 = *(const float4*)(arow + k0 + g*8 + 4);
        bf16x8 af;
        af[0] = (bf16_t)a0.x; af[1] = (bf16_t)a0.y; af[2] = (bf16_t)a0.z; af[3] = (bf16_t)a0.w;
        af[4] = (bf16_t)a1.x; af[5] = (bf16_t)a1.y; af[6] = (bf16_t)a1.z; af[7] = (bf16_t)a1.w;
        #pragma unroll
        for (int cf = 0; cf < 4; cf++) {
            bf16x8 bfr = *(const bf16x8*)(Wt + (size_t)(nbase + 16*cf + c)*DM + k0 + g*8);
            acc[cf] = __builtin_amdgcn_mfma_f32_16x16x32_bf16(af, bfr, acc[cf], 0, 0, 0);
        }
    }
    #pragma unroll
    for (int cf = 0; cf < 4; cf++) {
        int n = nbase + 16*cf + c;
        int hh = n >> 6, d = n & 63;
        float bv = bia[n];
        if (z < 2) {
            bf16_t* dst = (z == 0) ? QP : KP;
            #pragma unroll
            for (int j = 0; j < 4; j++) {
                int r = rbase + g*4 + j;
                int bb = r >> 11, s = r & 2047;
                dst[((size_t)(bb*HEADS + hh)*SEQ + s)*DK + d] = (bf16_t)(acc[cf][j] + bv);
            }
        } else {
            int r0 = rbase + g*4;
            int bb = r0 >> 11, s0 = r0 & 2047;
            bf16x4 pk;
            pk[0] = (bf16_t)(acc[cf][0] + bv); pk[1] = (bf16_t)(acc[cf][1] + bv);
            pk[2] = (bf16_t)(acc[cf][2] + bv); pk[3] = (bf16_t)(acc[cf][3] + bv);
            *(bf16x4*)(VT + ((size_t)(bb*HEADS + hh)*DK + d)*SEQ + s0) = pk;
        }
    }
}

// Flash attention: one block = (b, h, 64 q-rows); 4 waves x 16 q-rows each.
__global__ __launch_bounds__(256) void attn_kernel(
        const bf16_t* __restrict__ QP, const bf16_t* __restrict__ KP, const bf16_t* __restrict__ VT,
        const unsigned int* __restrict__ maskw, bf16_t* __restrict__ CTX) {
    int tid = threadIdx.x;
    int w = tid >> 6, u = tid & 63, c = u & 15, g = u >> 4;
    int b = blockIdx.z, h = blockIdx.y;
    int qb = blockIdx.x * 64 + w * 16;
    size_t bh = (size_t)(b * HEADS + h);
    const bf16_t* qp = QP + bh * SEQ * DK;
    const bf16_t* kp = KP + bh * SEQ * DK;
    const bf16_t* vt = VT + bh * DK * SEQ;
    const unsigned int* mw = maskw + (size_t)b * SEQ * (SEQ/32);
    __shared__ __attribute__((aligned(16))) unsigned char pbuf_all[4][2048];
    unsigned char* pb = pbuf_all[w];

    bf16x8 aq0 = *(const bf16x8*)(qp + (size_t)(qb + c)*DK + g*8);
    bf16x8 aq1 = *(const bf16x8*)(qp + (size_t)(qb + c)*DK + 32 + g*8);

    float mrow[4] = {-3e38f, -3e38f, -3e38f, -3e38f};
    float lrow[4] = {0.f, 0.f, 0.f, 0.f};
    f32x4 zero = {0.f, 0.f, 0.f, 0.f};
    f32x4 acc[4] = {zero, zero, zero, zero};

    for (int kt = 0; kt < SEQ/64; kt++) {
        int kb = kt * 64;
        f32x4 sf[4] = {zero, zero, zero, zero};
        #pragma unroll
        for (int cf = 0; cf < 4; cf++) {
            bf16x8 kf0 = *(const bf16x8*)(kp + (size_t)(kb + 16*cf + c)*DK + g*8);
            bf16x8 kf1 = *(const bf16x8*)(kp + (size_t)(kb + 16*cf + c)*DK + 32 + g*8);
            sf[cf] = __builtin_amdgcn_mfma_f32_16x16x32_bf16(aq0, kf0, sf[cf], 0, 0, 0);
            sf[cf] = __builtin_amdgcn_mfma_f32_16x16x32_bf16(aq1, kf1, sf[cf], 0, 0, 0);
        }
        #pragma unroll
        for (int j = 0; j < 4; j++) {
            int qrow = qb + g*4 + j;
            uint2 mv = *(const uint2*)(mw + (size_t)qrow*(SEQ/32) + (kb >> 5));
            float rmax = -3e38f;
            #pragma unroll
            for (int cf = 0; cf < 4; cf++) {
                unsigned int word = (cf < 2) ? mv.x : mv.y;
                float sv = sf[cf][j] * 0.125f;
                if ((word >> (((cf & 1) << 4) | c)) & 1u) sv = -1e9f;
                sf[cf][j] = sv;
                rmax = fmaxf(rmax, sv);
            }
            rmax = fmaxf(rmax, __shfl_xor(rmax, 1));
            rmax = fmaxf(rmax, __shfl_xor(rmax, 2));
            rmax = fmaxf(rmax, __shfl_xor(rmax, 4));
            rmax = fmaxf(rmax, __shfl_xor(rmax, 8));
            float mn = fmaxf(mrow[j], rmax);
            float alpha = __expf(mrow[j] - mn);
            mrow[j] = mn;
            float rsum = 0.f;
            #pragma unroll
            for (int cf = 0; cf < 4; cf++) {
                float p = __expf(sf[cf][j] - mn);
                sf[cf][j] = p;
                rsum += p;
            }
            rsum += __shfl_xor(rsum, 1);
            rsum += __shfl_xor(rsum, 2);
            rsum += __shfl_xor(rsum, 4);
            rsum += __shfl_xor(rsum, 8);
            lrow[j] = lrow[j] * alpha + rsum;
            #pragma unroll
            for (int cf = 0; cf < 4; cf++) acc[cf][j] *= alpha;
        }
        // P -> LDS (XOR-swizzled), then re-read as A-fragments for PV
        #pragma unroll
        for (int cf = 0; cf < 4; cf++) {
            #pragma unroll
            for (int j = 0; j < 4; j++) {
                int row = g*4 + j;
                int byte = (row * 128 + (16*cf + c) * 2) ^ ((row & 7) << 4);
                *(bf16_t*)(pb + byte) = (bf16_t)sf[cf][j];
            }
        }
        bf16x8 pa0, pa1;
        {
            int b0 = (c*128 + g*16) ^ ((c & 7) << 4);
            int b1 = (c*128 + 64 + g*16) ^ ((c & 7) << 4);
            pa0 = *(const bf16x8*)(pb + b0);
            pa1 = *(const bf16x8*)(pb + b1);
        }
        #pragma unroll
        for (int cf = 0; cf < 4; cf++) {
            bf16x8 v0 = *(const bf16x8*)(vt + (size_t)(16*cf + c)*SEQ + kb + g*8);
            bf16x8 v1 = *(const bf16x8*)(vt + (size_t)(16*cf + c)*SEQ + kb + 32 + g*8);
            acc[cf] = __builtin_amdgcn_mfma_f32_16x16x32_bf16(pa0, v0, acc[cf], 0, 0, 0);
            acc[cf] = __builtin_amdgcn_mfma_f32_16x16x32_bf16(pa1, v1, acc[cf], 0, 0, 0);
        }
    }
    #pragma unroll
    for (int cf = 0; cf < 4; cf++) {
        #pragma unroll
        for (int j = 0; j < 4; j++) {
            int tok = b * SEQ + qb + g*4 + j;
            CTX[(size_t)tok*DM + h*DK + 16*cf + c] = (bf16_t)(acc[cf][j] / lrow[j]);
        }
    }
}

// out = ctx @ Wfc + bfc + Q  (fp32 out)
__global__ __launch_bounds__(256) void out_gemm_kernel(
        const bf16_t* __restrict__ CTX, const bf16_t* __restrict__ WfcT,
        const float* __restrict__ bfc, const float* __restrict__ Qin, float* __restrict__ out) {
    int tid = threadIdx.x;
    int w = tid >> 6, u = tid & 63, c = u & 15, g = u >> 4;
    int rbase = blockIdx.x * 64 + w * 16;
    int nbase = blockIdx.y * 64;
    f32x4 zero = {0.f, 0.f, 0.f, 0.f};
    f32x4 acc[4] = {zero, zero, zero, zero};
    const bf16_t* arow = CTX + (size_t)(rbase + c) * DM;
    for (int k0 = 0; k0 < DM; k0 += 32) {
        bf16x8 af = *(const bf16x8*)(arow + k0 + g*8);
        #pragma unroll
        for (int cf = 0; cf < 4; cf++) {
            bf16x8 bfr = *(const bf16x8*)(WfcT + (size_t)(nbase + 16*cf + c)*DM + k0 + g*8);
            acc[cf] = __builtin_amdgcn_mfma_f32_16x16x32_bf16(af, bfr, acc[cf], 0, 0, 0);
        }
    }
    #pragma unroll
    for (int cf = 0; cf < 4; cf++) {
        int n = nbase + 16*cf + c;
        float bv = bfc[n];
        #pragma unroll
        for (int j = 0; j < 4; j++) {
            int r = rbase + g*4 + j;
            out[(size_t)r*DM + n] = acc[cf][j] + bv + Qin[(size_t)r*DM + n];
        }
    }
}

// In-place LayerNorm over rows of 768
__global__ __launch_bounds__(256) void ln_kernel(float* __restrict__ out,
        const float* __restrict__ gamma, const float* __restrict__ beta) {
    int w = threadIdx.x >> 6, u = threadIdx.x & 63;
    size_t row = (size_t)blockIdx.x * 4 + w;
    float x[12];
    float s = 0.f;
    #pragma unroll
    for (int i = 0; i < 12; i++) { x[i] = out[row*DM + i*64 + u]; s += x[i]; }
    #pragma unroll
    for (int d = 1; d < 64; d <<= 1) s += __shfl_xor(s, d);
    float mu = s * (1.0f/768.0f);
    float v = 0.f;
    #pragma unroll
    for (int i = 0; i < 12; i++) { float t = x[i] - mu; v += t*t; }
    #pragma unroll
    for (int d = 1; d < 64; d <<= 1) v += __shfl_xor(v, d);
    float rstd = rsqrtf(v * (1.0f/768.0f) + 1e-5f);
    #pragma unroll
    for (int i = 0; i < 12; i++)
        out[row*DM + i*64 + u] = (x[i] - mu) * rstd * gamma[i*64 + u] + beta[i*64 + u];
}

extern "C" void kernel_launch(void* const* d_in, const int* in_sizes, int n_in,
                              void* d_out, int out_size, void* d_ws, size_t ws_size,
                              hipStream_t stream) {
    const float* Q    = (const float*)d_in[0];
    const float* K    = (const float*)d_in[1];
    const float* V    = (const float*)d_in[2];
    const void*  mask = d_in[3];
    const float* WQ   = (const float*)d_in[4];
    const float* bQ   = (const float*)d_in[5];
    const float* WK   = (const float*)d_in[6];
    const float* bK   = (const float*)d_in[7];
    const float* WV   = (const float*)d_in[8];
    const float* bV   = (const float*)d_in[9];
    const float* Wfc  = (const float*)d_in[10];
    const float* bfc  = (const float*)d_in[11];
    const float* gam  = (const float*)d_in[12];
    const float* bet  = (const float*)d_in[13];
    float* out = (float*)d_out;
    char* ws = (char*)d_ws;

    int* flag            = (int*)(ws + OFF_FLAG);
    unsigned int* maskw  = (unsigned int*)(ws + OFF_MASK);
    bf16_t* WT           = (bf16_t*)(ws + OFF_WT);
    bf16_t* QP           = (bf16_t*)(ws + OFF_QP);
    bf16_t* KP           = (bf16_t*)(ws + OFF_KP);
    bf16_t* VT           = (bf16_t*)(ws + OFF_VT);
    bf16_t* CTX          = (bf16_t*)(ws + OFF_CTX);

    detect_mask_kernel<<<1, 64, 0, stream>>>((const unsigned char*)mask, flag);
    pack_mask_kernel<<<2048, 256, 0, stream>>>(mask, flag, maskw);
    wt_cvt_kernel<<<dim3(12, 12, 4), 256, 0, stream>>>(WQ, WK, WV, Wfc, WT);
    proj_gemm_kernel<<<dim3(128, 12, 3), 256, 0, stream>>>(Q, K, V, bQ, bK, bV, WT, QP, KP, VT);
    attn_kernel<<<dim3(32, HEADS, BATCH), 256, 0, stream>>>(QP, KP, VT, maskw, CTX);
    out_gemm_kernel<<<dim3(128, 12), 256, 0, stream>>>(CTX, WT + (size_t)3*DM*DM, bfc, Q, out);
    ln_kernel<<<2048, 256, 0, stream>>>(out, gam, bet);
}

// Round 2
// 653.638 us; speedup vs baseline: 1.5150x; 1.5150x over previous
//
#include <hip/hip_runtime.h>
#include <stdint.h>

#define DM   768
#define HEADS 12
#define DK    64
#define SEQ  2048
#define BATCH  4

typedef __bf16 bf16_t;
typedef __bf16 bf16x8 __attribute__((ext_vector_type(8)));
typedef __bf16 bf16x4 __attribute__((ext_vector_type(4)));
typedef float  f32x4  __attribute__((ext_vector_type(4)));

// ---- workspace layout (bytes), all 256-aligned ----
#define OFF_FLAG 0
#define OFF_MASK 256
#define SZ_MASK  (BATCH*SEQ*(SEQ/32)*4)          // 2 MB packed mask bits
#define OFF_WT   (OFF_MASK + SZ_MASK)
#define SZ_WT1   (DM*DM*2)                       // one bf16 weight (transposed)
#define OFF_XB   (OFF_WT + 4*SZ_WT1)             // bf16 Q,K,V inputs (3 x 12.6MB)
#define SZ_X     (BATCH*SEQ*DM*2)
#define OFF_QP   (OFF_XB + 3*SZ_X)
#define SZ_PROJ  (BATCH*HEADS*SEQ*DK*2)          // 12.6 MB
#define OFF_KP   (OFF_QP + SZ_PROJ)
#define OFF_VT   (OFF_KP + SZ_PROJ)
// CTX aliases XB slot 0 (bf16 Q): Q-slot last read by proj z=0, CTX written later.

__device__ __forceinline__ void gload_lds16(const bf16_t* g, bf16_t* l) {
    __builtin_amdgcn_global_load_lds((const __attribute__((address_space(1))) unsigned int*)g,
                                     (__attribute__((address_space(3))) unsigned int*)l, 16, 0, 0);
}

// Detect mask element width: int32 0/1 values have bytes 1,2,3 zero.
__global__ void detect_mask_kernel(const unsigned char* __restrict__ m, int* flag) {
    int u = threadIdx.x;  // 64 threads
    int any = m[4*u+1] | m[4*u+2] | m[4*u+3];
    unsigned long long b = __ballot(any != 0);
    if (u == 0) *flag = (b == 0ULL) ? 1 : 0;   // 1 => int32 layout, 0 => byte layout
}

// Pack mask (True => masked) into bits: word[e>>5] bit (e&31).
__global__ void pack_mask_kernel(const void* __restrict__ mraw, const int* __restrict__ flag,
                                 unsigned int* __restrict__ words) {
    const unsigned int total = BATCH*SEQ*SEQ;
    const int is32 = *flag;
    const int* mi = (const int*)mraw;
    const unsigned char* mb = (const unsigned char*)mraw;
    unsigned int stride = gridDim.x * blockDim.x;
    unsigned int lane = threadIdx.x & 63u;
    for (unsigned int e = blockIdx.x * blockDim.x + threadIdx.x; e < total; e += stride) {
        int v = is32 ? (mi[e] != 0) : (mb[e] != 0);
        unsigned long long bal = __ballot(v);
        if ((lane & 31u) == 0u)
            words[e >> 5] = (unsigned int)(bal >> ((lane >> 5) * 32u));
    }
}

// Transpose + convert weights to bf16: W[k][n] f32 -> Wt[n][k] bf16
__global__ void wt_cvt_kernel(const float* __restrict__ W0, const float* __restrict__ W1,
                              const float* __restrict__ W2, const float* __restrict__ W3,
                              bf16_t* __restrict__ dst) {
    const float* W = blockIdx.z == 0 ? W0 : blockIdx.z == 1 ? W1 : blockIdx.z == 2 ? W2 : W3;
    bf16_t* out = dst + (size_t)blockIdx.z * DM * DM;
    __shared__ float tile[64][65];
    int w = threadIdx.x >> 6, u = threadIdx.x & 63;
    int kb = blockIdx.x * 64, nb = blockIdx.y * 64;
    #pragma unroll
    for (int i = 0; i < 16; i++)
        tile[w + 4*i][u] = W[(size_t)(kb + w + 4*i)*DM + nb + u];
    __syncthreads();
    #pragma unroll
    for (int i = 0; i < 16; i++)
        out[(size_t)(nb + w + 4*i)*DM + kb + u] = (bf16_t)tile[u][w + 4*i];
}

// Convert fp32 inputs to bf16
__global__ void xcvt_kernel(const float* __restrict__ Q, const float* __restrict__ K,
                            const float* __restrict__ V, bf16_t* __restrict__ XB) {
    int z = blockIdx.y;
    const float* src = z == 0 ? Q : z == 1 ? K : V;
    bf16_t* dst = XB + (size_t)z * BATCH*SEQ*DM;
    size_t i = ((size_t)blockIdx.x * blockDim.x + threadIdx.x) * 8;
    float4 a = *(const float4*)(src + i);
    float4 b = *(const float4*)(src + i + 4);
    bf16x8 o;
    o[0]=(bf16_t)a.x; o[1]=(bf16_t)a.y; o[2]=(bf16_t)a.z; o[3]=(bf16_t)a.w;
    o[4]=(bf16_t)b.x; o[5]=(bf16_t)b.y; o[6]=(bf16_t)b.z; o[7]=(bf16_t)b.w;
    *(bf16x8*)(dst + i) = o;
}

// m97-style 128x128 tile mainloop: A[M x 768] bf16, B[N x 768] bf16 (row = out col), K=768
__device__ __forceinline__ void mm_mainloop(const bf16_t* __restrict__ Aptr,
                                            const bf16_t* __restrict__ Bptr,
                                            bf16_t* As, bf16_t* Bs,
                                            f32x4 acc[4][4], int bm, int bn) {
    int tid = threadIdx.x, w = tid >> 6, u = tid & 63, c = u & 15, g = u >> 4;
    int wr = w >> 1, wc = w & 1;
    for (int k0 = 0; k0 < DM; k0 += 64) {
        #pragma unroll
        for (int i = 0; i < 4; i++) {
            int q = i*256 + tid;
            int row = q >> 3, col8 = q & 7;
            gload_lds16(Aptr + (size_t)(bm*128 + row)*DM + k0 + col8*8, As + (i*256 + w*64)*8);
            gload_lds16(Bptr + (size_t)(bn*128 + row)*DM + k0 + col8*8, Bs + (i*256 + w*64)*8);
        }
        __syncthreads();
        #pragma unroll
        for (int kk = 0; kk < 2; kk++) {
            bf16x8 a[4], bfr[4];
            #pragma unroll
            for (int mi = 0; mi < 4; mi++)
                a[mi] = *(const bf16x8*)(As + (wr*64 + mi*16 + c)*64 + kk*32 + g*8);
            #pragma unroll
            for (int ni = 0; ni < 4; ni++)
                bfr[ni] = *(const bf16x8*)(Bs + (wc*64 + ni*16 + c)*64 + kk*32 + g*8);
            #pragma unroll
            for (int mi = 0; mi < 4; mi++)
                #pragma unroll
                for (int ni = 0; ni < 4; ni++)
                    acc[mi][ni] = __builtin_amdgcn_mfma_f32_16x16x32_bf16(a[mi], bfr[ni], acc[mi][ni], 0, 0, 0);
        }
        __syncthreads();
    }
}

// QKV projections: z=0 Q (scaled 0.125), z=1 K, z=2 V (transposed store)
__global__ __launch_bounds__(256) void proj128_kernel(
        const bf16_t* __restrict__ XB, const bf16_t* __restrict__ WT,
        const float* __restrict__ bQ, const float* __restrict__ bK, const float* __restrict__ bV,
        bf16_t* __restrict__ QP, bf16_t* __restrict__ KP, bf16_t* __restrict__ VT) {
    int z = blockIdx.z;
    const bf16_t* Aptr = XB + (size_t)z * BATCH*SEQ*DM;
    const bf16_t* Bptr = WT + (size_t)z * DM * DM;
    const float* bias = z == 0 ? bQ : z == 1 ? bK : bV;
    float scale = (z == 0) ? 0.125f : 1.0f;
    __shared__ __align__(16) bf16_t As[128*64], Bs[128*64];
    int tid = threadIdx.x, w = tid >> 6, u = tid & 63, c = u & 15, g = u >> 4;
    int wr = w >> 1, wc = w & 1;
    int bm = blockIdx.x, bn = blockIdx.y;
    f32x4 zero = {0.f,0.f,0.f,0.f};
    f32x4 acc[4][4] = {{zero,zero,zero,zero},{zero,zero,zero,zero},
                       {zero,zero,zero,zero},{zero,zero,zero,zero}};
    mm_mainloop(Aptr, Bptr, As, Bs, acc, bm, bn);
    int h = bn*2 + wc;          // head (uniform per wave)
    #pragma unroll
    for (int ni = 0; ni < 4; ni++) {
        int d = ni*16 + c;
        float bv = bias[h*64 + d];
        if (z < 2) {
            bf16_t* dst = (z == 0) ? QP : KP;
            #pragma unroll
            for (int mi = 0; mi < 4; mi++)
                #pragma unroll
                for (int j = 0; j < 4; j++) {
                    int r = bm*128 + wr*64 + mi*16 + 4*g + j;
                    int bidx = r >> 11, s = r & 2047;
                    dst[(((size_t)bidx*HEADS + h)*SEQ + s)*DK + d] = (bf16_t)((acc[mi][ni][j] + bv)*scale);
                }
        } else {
            #pragma unroll
            for (int mi = 0; mi < 4; mi++) {
                bf16x4 pk;
                #pragma unroll
                for (int j = 0; j < 4; j++) pk[j] = (bf16_t)(acc[mi][ni][j] + bv);
                int r0 = bm*128 + wr*64 + mi*16 + 4*g;
                int bidx = r0 >> 11, s0 = r0 & 2047;
                *(bf16x4*)(VT + (((size_t)bidx*HEADS + h)*DK + d)*SEQ + s0) = pk;
            }
        }
    }
}

// Output projection: out = CTX @ Wfc + bfc + Q (fp32)
__global__ __launch_bounds__(256) void out128_kernel(
        const bf16_t* __restrict__ CTX, const bf16_t* __restrict__ WfcT,
        const float* __restrict__ bfc, const float* __restrict__ Qres, float* __restrict__ out) {
    __shared__ __align__(16) bf16_t As[128*64], Bs[128*64];
    int tid = threadIdx.x, w = tid >> 6, u = tid & 63, c = u & 15, g = u >> 4;
    int wr = w >> 1, wc = w & 1;
    int bm = blockIdx.x, bn = blockIdx.y;
    f32x4 zero = {0.f,0.f,0.f,0.f};
    f32x4 acc[4][4] = {{zero,zero,zero,zero},{zero,zero,zero,zero},
                       {zero,zero,zero,zero},{zero,zero,zero,zero}};
    mm_mainloop(CTX, WfcT, As, Bs, acc, bm, bn);
    #pragma unroll
    for (int ni = 0; ni < 4; ni++) {
        int n = bn*128 + wc*64 + ni*16 + c;
        float bv = bfc[n];
        #pragma unroll
        for (int mi = 0; mi < 4; mi++)
            #pragma unroll
            for (int j = 0; j < 4; j++) {
                int r = bm*128 + wr*64 + mi*16 + 4*g + j;
                out[(size_t)r*DM + n] = acc[mi][ni][j] + bv + Qres[(size_t)r*DM + n];
            }
    }
}

// Flash attention, swapped-QK^T: one block = (b, h, 64 q-rows); 4 waves x 16 q-rows.
// Lane (c,g) owns q = qb+c; holds S^T scores k_local = 16cf+4g+j.
__global__ __launch_bounds__(256) void attn_kernel(
        const bf16_t* __restrict__ QP, const bf16_t* __restrict__ KP, const bf16_t* __restrict__ VT,
        const unsigned int* __restrict__ maskw, bf16_t* __restrict__ CTX) {
    int tid = threadIdx.x, w = tid >> 6, u = tid & 63, c = u & 15, g = u >> 4;
    int b = blockIdx.z, h = blockIdx.y;
    int qb = blockIdx.x * 64 + w * 16;
    size_t bh = (size_t)(b * HEADS + h);
    const bf16_t* qp = QP + bh * SEQ * DK;
    const bf16_t* kp = KP + bh * SEQ * DK;
    const bf16_t* vt = VT + bh * DK * SEQ;
    const unsigned int* mw = maskw + ((size_t)b * SEQ + qb + c) * (SEQ/32);
    __shared__ __align__(16) unsigned char pball[4][2048];
    unsigned char* pb = pball[w];
    int swz = (c & 7) << 4;

    bf16x8 qf0 = *(const bf16x8*)(qp + (size_t)(qb + c)*DK + g*8);
    bf16x8 qf1 = *(const bf16x8*)(qp + (size_t)(qb + c)*DK + 32 + g*8);

    float m = -3e38f, l = 0.f;
    f32x4 zero = {0.f,0.f,0.f,0.f};
    f32x4 acc[4] = {zero, zero, zero, zero};   // acc[cf][j] = O^T[d=16cf+4g+j][q=c]

    for (int kt = 0; kt < SEQ/64; kt++) {
        int kb = kt * 64;
        uint2 mv = *(const uint2*)(mw + (kb >> 5));
        f32x4 s4[4] = {zero, zero, zero, zero};
        #pragma unroll
        for (int cf = 0; cf < 4; cf++) {
            bf16x8 kf0 = *(const bf16x8*)(kp + (size_t)(kb + 16*cf + c)*DK + g*8);
            bf16x8 kf1 = *(const bf16x8*)(kp + (size_t)(kb + 16*cf + c)*DK + 32 + g*8);
            s4[cf] = __builtin_amdgcn_mfma_f32_16x16x32_bf16(kf0, qf0, s4[cf], 0, 0, 0);
            s4[cf] = __builtin_amdgcn_mfma_f32_16x16x32_bf16(kf1, qf1, s4[cf], 0, 0, 0);
        }
        // mask + row max (row is lane-local: 15 fmax + 2 shfl)
        float rmax = -3e38f;
        #pragma unroll
        for (int cf = 0; cf < 4; cf++) {
            unsigned int word = (cf & 2) ? mv.y : mv.x;
            #pragma unroll
            for (int j = 0; j < 4; j++) {
                float sv = s4[cf][j];
                if ((word >> (((cf & 1) << 4) + 4*g + j)) & 1u) sv = -1e9f;
                s4[cf][j] = sv;
                rmax = fmaxf(rmax, sv);
            }
        }
        rmax = fmaxf(rmax, __shfl_xor(rmax, 16));
        rmax = fmaxf(rmax, __shfl_xor(rmax, 32));
        float mn = fmaxf(m, rmax);
        float alpha = __expf(m - mn);
        m = mn;
        float rsum = 0.f;
        #pragma unroll
        for (int cf = 0; cf < 4; cf++)
            #pragma unroll
            for (int j = 0; j < 4; j++) {
                float p = __expf(s4[cf][j] - mn);
                s4[cf][j] = p;
                rsum += p;
            }
        rsum += __shfl_xor(rsum, 16);
        rsum += __shfl_xor(rsum, 32);
        l = l * alpha + rsum;
        #pragma unroll
        for (int cf = 0; cf < 4; cf++)
            #pragma unroll
            for (int j = 0; j < 4; j++) acc[cf][j] *= alpha;
        // P^T row (q=c) -> LDS, 16B-granule XOR swizzle (2-way conflicts only)
        #pragma unroll
        for (int cf = 0; cf < 4; cf++) {
            bf16x4 pk;
            #pragma unroll
            for (int j = 0; j < 4; j++) pk[j] = (bf16_t)s4[cf][j];
            int base = 32*cf + 8*g;
            int byte = c*128 + ((base & ~15) ^ swz) + (base & 15);
            *(bf16x4*)(pb + byte) = pk;
        }
        bf16x8 pa0 = *(const bf16x8*)(pb + c*128 + ((g << 4) ^ swz));
        bf16x8 pa1 = *(const bf16x8*)(pb + c*128 + (((4 + g) << 4) ^ swz));
        #pragma unroll
        for (int cf = 0; cf < 4; cf++) {
            bf16x8 vf0 = *(const bf16x8*)(vt + (size_t)(16*cf + c)*SEQ + kb + g*8);
            bf16x8 vf1 = *(const bf16x8*)(vt + (size_t)(16*cf + c)*SEQ + kb + 32 + g*8);
            acc[cf] = __builtin_amdgcn_mfma_f32_16x16x32_bf16(vf0, pa0, acc[cf], 0, 0, 0);
            acc[cf] = __builtin_amdgcn_mfma_f32_16x16x32_bf16(vf1, pa1, acc[cf], 0, 0, 0);
        }
    }
    float inv = 1.0f / l;
    size_t obase = ((size_t)(b * SEQ) + qb + c) * DM + h * DK;
    #pragma unroll
    for (int cf = 0; cf < 4; cf++) {
        bf16x4 ok;
        #pragma unroll
        for (int j = 0; j < 4; j++) ok[j] = (bf16_t)(acc[cf][j] * inv);
        *(bf16x4*)(CTX + obase + 16*cf + 4*g) = ok;
    }
}

// In-place LayerNorm over rows of 768
__global__ __launch_bounds__(256) void ln_kernel(float* __restrict__ out,
        const float* __restrict__ gamma, const float* __restrict__ beta) {
    int w = threadIdx.x >> 6, u = threadIdx.x & 63;
    size_t row = (size_t)blockIdx.x * 4 + w;
    float x[12];
    float s = 0.f;
    #pragma unroll
    for (int i = 0; i < 12; i++) { x[i] = out[row*DM + i*64 + u]; s += x[i]; }
    #pragma unroll
    for (int d = 1; d < 64; d <<= 1) s += __shfl_xor(s, d);
    float mu = s * (1.0f/768.0f);
    float v = 0.f;
    #pragma unroll
    for (int i = 0; i < 12; i++) { float t = x[i] - mu; v += t*t; }
    #pragma unroll
    for (int d = 1; d < 64; d <<= 1) v += __shfl_xor(v, d);
    float rstd = rsqrtf(v * (1.0f/768.0f) + 1e-5f);
    #pragma unroll
    for (int i = 0; i < 12; i++)
        out[row*DM + i*64 + u] = (x[i] - mu) * rstd * gamma[i*64 + u] + beta[i*64 + u];
}

extern "C" void kernel_launch(void* const* d_in, const int* in_sizes, int n_in,
                              void* d_out, int out_size, void* d_ws, size_t ws_size,
                              hipStream_t stream) {
    const float* Q    = (const float*)d_in[0];
    const float* K    = (const float*)d_in[1];
    const float* V    = (const float*)d_in[2];
    const void*  mask = d_in[3];
    const float* WQ   = (const float*)d_in[4];
    const float* bQ   = (const float*)d_in[5];
    const float* WK   = (const float*)d_in[6];
    const float* bK   = (const float*)d_in[7];
    const float* WV   = (const float*)d_in[8];
    const float* bV   = (const float*)d_in[9];
    const float* Wfc  = (const float*)d_in[10];
    const float* bfc  = (const float*)d_in[11];
    const float* gam  = (const float*)d_in[12];
    const float* bet  = (const float*)d_in[13];
    float* out = (float*)d_out;
    char* ws = (char*)d_ws;

    int* flag            = (int*)(ws + OFF_FLAG);
    unsigned int* maskw  = (unsigned int*)(ws + OFF_MASK);
    bf16_t* WT           = (bf16_t*)(ws + OFF_WT);
    bf16_t* XB           = (bf16_t*)(ws + OFF_XB);
    bf16_t* QP           = (bf16_t*)(ws + OFF_QP);
    bf16_t* KP           = (bf16_t*)(ws + OFF_KP);
    bf16_t* VT           = (bf16_t*)(ws + OFF_VT);
    bf16_t* CTX          = XB;   // alias bf16-Q slot (dead after proj z=0)

    detect_mask_kernel<<<1, 64, 0, stream>>>((const unsigned char*)mask, flag);
    pack_mask_kernel<<<2048, 256, 0, stream>>>(mask, flag, maskw);
    xcvt_kernel<<<dim3(3072, 3), 256, 0, stream>>>(Q, K, V, XB);
    wt_cvt_kernel<<<dim3(12, 12, 4), 256, 0, stream>>>(WQ, WK, WV, Wfc, WT);
    proj128_kernel<<<dim3(64, 6, 3), 256, 0, stream>>>(XB, WT, bQ, bK, bV, QP, KP, VT);
    attn_kernel<<<dim3(SEQ/64, HEADS, BATCH), 256, 0, stream>>>(QP, KP, VT, maskw, CTX);
    out128_kernel<<<dim3(64, 6), 256, 0, stream>>>(CTX, WT + (size_t)3*DM*DM, bfc, Q, out);
    ln_kernel<<<2048, 256, 0, stream>>>(out, gam, bet);
}

// Round 3
// 448.699 us; speedup vs baseline: 2.2070x; 1.4567x over previous
//
#include <hip/hip_runtime.h>
#include <stdint.h>

#define DM   768
#define HEADS 12
#define DK    64
#define SEQ  2048
#define BATCH  4

typedef __bf16 bf16_t;
typedef __bf16 bf16x8 __attribute__((ext_vector_type(8)));
typedef __bf16 bf16x4 __attribute__((ext_vector_type(4)));
typedef float  f32x4  __attribute__((ext_vector_type(4)));
typedef float  f32x16 __attribute__((ext_vector_type(16)));
typedef unsigned u32x4 __attribute__((ext_vector_type(4)));

#define LOG2E 1.44269504f
#define MASKVAL (-1.442695e9f)

// ---- workspace layout (bytes), all 256-aligned ----
#define OFF_FLAG 0
#define OFF_MASK 256
#define SZ_MASK  (BATCH*SEQ*(SEQ/32)*4)          // 2 MB packed mask bits
#define OFF_WT   (OFF_MASK + SZ_MASK)
#define SZ_WT1   (DM*DM*2)                       // one bf16 weight (transposed)
#define OFF_XB   (OFF_WT + 4*SZ_WT1)             // bf16 Q,K,V inputs (3 x 12.6MB)
#define SZ_X     (BATCH*SEQ*DM*2)
#define OFF_QP   (OFF_XB + 3*SZ_X)
#define SZ_PROJ  (BATCH*HEADS*SEQ*DK*2)          // 12.6 MB
#define OFF_KP   (OFF_QP + SZ_PROJ)
#define OFF_VT   (OFF_KP + SZ_PROJ)
// CTX aliases XB slot 0 (bf16 Q): dead after proj z=0.

__device__ __forceinline__ void gload_lds16(const bf16_t* g, bf16_t* l) {
    __builtin_amdgcn_global_load_lds((const __attribute__((address_space(1))) unsigned int*)g,
                                     (__attribute__((address_space(3))) unsigned int*)l, 16, 0, 0);
}

__device__ __forceinline__ unsigned pack2(float lo, float hi) {
    union { bf16_t b[2]; unsigned u; } x;
    x.b[0] = (bf16_t)lo; x.b[1] = (bf16_t)hi;
    return x.u;
}

// Detect mask element width: int32 0/1 values have bytes 1,2,3 zero.
__global__ void detect_mask_kernel(const unsigned char* __restrict__ m, int* flag) {
    int u = threadIdx.x;  // 64 threads
    int any = m[4*u+1] | m[4*u+2] | m[4*u+3];
    unsigned long long b = __ballot(any != 0);
    if (u == 0) *flag = (b == 0ULL) ? 1 : 0;
}

// Pack mask (True => masked) into bits.
__global__ void pack_mask_kernel(const void* __restrict__ mraw, const int* __restrict__ flag,
                                 unsigned int* __restrict__ words) {
    const unsigned int total = BATCH*SEQ*SEQ;
    const int is32 = *flag;
    const int* mi = (const int*)mraw;
    const unsigned char* mb = (const unsigned char*)mraw;
    unsigned int stride = gridDim.x * blockDim.x;
    unsigned int lane = threadIdx.x & 63u;
    for (unsigned int e = blockIdx.x * blockDim.x + threadIdx.x; e < total; e += stride) {
        int v = is32 ? (mi[e] != 0) : (mb[e] != 0);
        unsigned long long bal = __ballot(v);
        if ((lane & 31u) == 0u)
            words[e >> 5] = (unsigned int)(bal >> ((lane >> 5) * 32u));
    }
}

// Transpose + convert weights to bf16: W[k][n] f32 -> Wt[n][k] bf16
__global__ void wt_cvt_kernel(const float* __restrict__ W0, const float* __restrict__ W1,
                              const float* __restrict__ W2, const float* __restrict__ W3,
                              bf16_t* __restrict__ dst) {
    const float* W = blockIdx.z == 0 ? W0 : blockIdx.z == 1 ? W1 : blockIdx.z == 2 ? W2 : W3;
    bf16_t* out = dst + (size_t)blockIdx.z * DM * DM;
    __shared__ float tile[64][65];
    int w = threadIdx.x >> 6, u = threadIdx.x & 63;
    int kb = blockIdx.x * 64, nb = blockIdx.y * 64;
    #pragma unroll
    for (int i = 0; i < 16; i++)
        tile[w + 4*i][u] = W[(size_t)(kb + w + 4*i)*DM + nb + u];
    __syncthreads();
    #pragma unroll
    for (int i = 0; i < 16; i++)
        out[(size_t)(nb + w + 4*i)*DM + kb + u] = (bf16_t)tile[u][w + 4*i];
}

// Convert fp32 inputs to bf16
__global__ void xcvt_kernel(const float* __restrict__ Q, const float* __restrict__ K,
                            const float* __restrict__ V, bf16_t* __restrict__ XB) {
    int z = blockIdx.y;
    const float* src = z == 0 ? Q : z == 1 ? K : V;
    bf16_t* dst = XB + (size_t)z * BATCH*SEQ*DM;
    size_t i = ((size_t)blockIdx.x * blockDim.x + threadIdx.x) * 8;
    float4 a = *(const float4*)(src + i);
    float4 b = *(const float4*)(src + i + 4);
    bf16x8 o;
    o[0]=(bf16_t)a.x; o[1]=(bf16_t)a.y; o[2]=(bf16_t)a.z; o[3]=(bf16_t)a.w;
    o[4]=(bf16_t)b.x; o[5]=(bf16_t)b.y; o[6]=(bf16_t)b.z; o[7]=(bf16_t)b.w;
    *(bf16x8*)(dst + i) = o;
}

// m97-style 128x128 tile mainloop
__device__ __forceinline__ void mm_mainloop(const bf16_t* __restrict__ Aptr,
                                            const bf16_t* __restrict__ Bptr,
                                            bf16_t* As, bf16_t* Bs,
                                            f32x4 acc[4][4], int bm, int bn) {
    int tid = threadIdx.x, w = tid >> 6, u = tid & 63, c = u & 15, g = u >> 4;
    int wr = w >> 1, wc = w & 1;
    for (int k0 = 0; k0 < DM; k0 += 64) {
        #pragma unroll
        for (int i = 0; i < 4; i++) {
            int q = i*256 + tid;
            int row = q >> 3, col8 = q & 7;
            gload_lds16(Aptr + (size_t)(bm*128 + row)*DM + k0 + col8*8, As + (i*256 + w*64)*8);
            gload_lds16(Bptr + (size_t)(bn*128 + row)*DM + k0 + col8*8, Bs + (i*256 + w*64)*8);
        }
        __syncthreads();
        #pragma unroll
        for (int kk = 0; kk < 2; kk++) {
            bf16x8 a[4], bfr[4];
            #pragma unroll
            for (int mi = 0; mi < 4; mi++)
                a[mi] = *(const bf16x8*)(As + (wr*64 + mi*16 + c)*64 + kk*32 + g*8);
            #pragma unroll
            for (int ni = 0; ni < 4; ni++)
                bfr[ni] = *(const bf16x8*)(Bs + (wc*64 + ni*16 + c)*64 + kk*32 + g*8);
            #pragma unroll
            for (int mi = 0; mi < 4; mi++)
                #pragma unroll
                for (int ni = 0; ni < 4; ni++)
                    acc[mi][ni] = __builtin_amdgcn_mfma_f32_16x16x32_bf16(a[mi], bfr[ni], acc[mi][ni], 0, 0, 0);
        }
        __syncthreads();
    }
}

// QKV projections: z=0 Q (scaled 0.125*log2e), z=1 K, z=2 V (transposed store)
__global__ __launch_bounds__(256) void proj128_kernel(
        const bf16_t* __restrict__ XB, const bf16_t* __restrict__ WT,
        const float* __restrict__ bQ, const float* __restrict__ bK, const float* __restrict__ bV,
        bf16_t* __restrict__ QP, bf16_t* __restrict__ KP, bf16_t* __restrict__ VT) {
    int z = blockIdx.z;
    const bf16_t* Aptr = XB + (size_t)z * BATCH*SEQ*DM;
    const bf16_t* Bptr = WT + (size_t)z * DM * DM;
    const float* bias = z == 0 ? bQ : z == 1 ? bK : bV;
    float scale = (z == 0) ? 0.125f * LOG2E : 1.0f;
    __shared__ __align__(16) bf16_t As[128*64], Bs[128*64];
    int tid = threadIdx.x, w = tid >> 6, u = tid & 63, c = u & 15, g = u >> 4;
    int wr = w >> 1, wc = w & 1;
    int bm = blockIdx.x, bn = blockIdx.y;
    f32x4 zero = {0.f,0.f,0.f,0.f};
    f32x4 acc[4][4] = {{zero,zero,zero,zero},{zero,zero,zero,zero},
                       {zero,zero,zero,zero},{zero,zero,zero,zero}};
    mm_mainloop(Aptr, Bptr, As, Bs, acc, bm, bn);
    int h = bn*2 + wc;
    #pragma unroll
    for (int ni = 0; ni < 4; ni++) {
        int d = ni*16 + c;
        float bv = bias[h*64 + d];
        if (z < 2) {
            bf16_t* dst = (z == 0) ? QP : KP;
            #pragma unroll
            for (int mi = 0; mi < 4; mi++)
                #pragma unroll
                for (int j = 0; j < 4; j++) {
                    int r = bm*128 + wr*64 + mi*16 + 4*g + j;
                    int bidx = r >> 11, s = r & 2047;
                    dst[(((size_t)bidx*HEADS + h)*SEQ + s)*DK + d] = (bf16_t)((acc[mi][ni][j] + bv)*scale);
                }
        } else {
            #pragma unroll
            for (int mi = 0; mi < 4; mi++) {
                bf16x4 pk;
                #pragma unroll
                for (int j = 0; j < 4; j++) pk[j] = (bf16_t)(acc[mi][ni][j] + bv);
                int r0 = bm*128 + wr*64 + mi*16 + 4*g;
                int bidx = r0 >> 11, s0 = r0 & 2047;
                *(bf16x4*)(VT + (((size_t)bidx*HEADS + h)*DK + d)*SEQ + s0) = pk;
            }
        }
    }
}

// Output projection: out = CTX @ Wfc + bfc + Q (fp32)
__global__ __launch_bounds__(256) void out128_kernel(
        const bf16_t* __restrict__ CTX, const bf16_t* __restrict__ WfcT,
        const float* __restrict__ bfc, const float* __restrict__ Qres, float* __restrict__ out) {
    __shared__ __align__(16) bf16_t As[128*64], Bs[128*64];
    int tid = threadIdx.x, w = tid >> 6, u = tid & 63, c = u & 15, g = u >> 4;
    int wr = w >> 1, wc = w & 1;
    int bm = blockIdx.x, bn = blockIdx.y;
    f32x4 zero = {0.f,0.f,0.f,0.f};
    f32x4 acc[4][4] = {{zero,zero,zero,zero},{zero,zero,zero,zero},
                       {zero,zero,zero,zero},{zero,zero,zero,zero}};
    mm_mainloop(CTX, WfcT, As, Bs, acc, bm, bn);
    #pragma unroll
    for (int ni = 0; ni < 4; ni++) {
        int n = bn*128 + wc*64 + ni*16 + c;
        float bv = bfc[n];
        #pragma unroll
        for (int mi = 0; mi < 4; mi++)
            #pragma unroll
            for (int j = 0; j < 4; j++) {
                int r = bm*128 + wr*64 + mi*16 + 4*g + j;
                out[(size_t)r*DM + n] = acc[mi][ni][j] + bv + Qres[(size_t)r*DM + n];
            }
    }
}

// ---------------- Flash attention, 32x32 MFMA + LDS-staged K/V ----------------
// Block: 4 waves x 32 q-rows = 128 q-rows. KVBLK=64. K/V double-buffered in LDS
// with 16B-chunk XOR swizzle. Swapped QK^T: lane u owns q-col = u&31; S^T reg r
// holds k = (r&3)+8*(r>>2)+4*(u>>5) (+32 per stile). P->bf16 via pack+permlane.
__global__ __launch_bounds__(256) void attn_kernel(
        const bf16_t* __restrict__ QP, const bf16_t* __restrict__ KP, const bf16_t* __restrict__ VT,
        const unsigned int* __restrict__ maskw, bf16_t* __restrict__ CTX) {
    __shared__ __align__(16) bf16_t kbuf[2][64*64];
    __shared__ __align__(16) bf16_t vbuf[2][64*64];
    int tid = threadIdx.x, w = tid >> 6, u = tid & 63;
    int qc = u & 31, hi = u >> 5;
    int b = blockIdx.z, h = blockIdx.y;
    int qg = blockIdx.x * 128 + w * 32 + qc;      // this lane's q row
    size_t bh = (size_t)(b * HEADS + h);
    const bf16_t* qp = QP + bh * SEQ * DK;
    const bf16_t* kp = KP + bh * SEQ * DK;
    const bf16_t* vt = VT + bh * DK * SEQ;
    const unsigned int* mwq = maskw + ((size_t)b * SEQ + qg) * (SEQ/32);

    // persistent Q fragments (B-operand): qf[t] = Q[qg][16t+8hi .. +8]
    bf16x8 qf[4];
    #pragma unroll
    for (int t = 0; t < 4; t++)
        qf[t] = *(const bf16x8*)(qp + (size_t)qg*DK + 16*t + 8*hi);

    // staging indices
    int sr = tid >> 3, scc = tid & 7;

    f32x16 zz = {0,0,0,0,0,0,0,0,0,0,0,0,0,0,0,0};
    f32x16 acc0 = zz, acc1 = zz;
    float mrun = -3e38f, lsum = 0.f;

    // prologue: stage tile 0 into buf 0
    #pragma unroll
    for (int i = 0; i < 2; i++) {
        int r = i*32 + sr;
        int gc = (scc ^ (r & 7)) << 3;
        gload_lds16(kp + (size_t)r*DK + gc,       &kbuf[0][0] + i*2048 + tid*8);
        gload_lds16(vt + (size_t)r*SEQ + 0 + gc,  &vbuf[0][0] + i*2048 + tid*8);
    }
    __syncthreads();

    for (int kt = 0; kt < SEQ/64; kt++) {
        int kb = kt * 64;
        int cur = kt & 1;
        // stage next tile into other buffer
        if (kt + 1 < SEQ/64) {
            int nkb = kb + 64;
            #pragma unroll
            for (int i = 0; i < 2; i++) {
                int r = i*32 + sr;
                int gc = (scc ^ (r & 7)) << 3;
                gload_lds16(kp + (size_t)(nkb + r)*DK + gc, &kbuf[cur^1][0] + i*2048 + tid*8);
                gload_lds16(vt + (size_t)r*SEQ + nkb + gc,  &vbuf[cur^1][0] + i*2048 + tid*8);
            }
        }
        const bf16_t* kl = &kbuf[cur][0];
        const bf16_t* vl = &vbuf[cur][0];
        uint2 mv = *(const uint2*)(mwq + (kb >> 5));

        // QK^T (S^T): 8 x mfma_32x32x16
        f32x16 s0 = zz, s1 = zz;
        __builtin_amdgcn_s_setprio(1);
        #pragma unroll
        for (int t = 0; t < 4; t++) {
            int col = (16*t + 8*hi);
            int r0 = qc, r1 = 32 + qc;
            bf16x8 k0 = *(const bf16x8*)(kl + r0*64 + (col ^ ((r0 & 7) << 3)));
            bf16x8 k1 = *(const bf16x8*)(kl + r1*64 + (col ^ ((r1 & 7) << 3)));
            s0 = __builtin_amdgcn_mfma_f32_32x32x16_bf16(k0, qf[t], s0, 0, 0, 0);
            s1 = __builtin_amdgcn_mfma_f32_32x32x16_bf16(k1, qf[t], s1, 0, 0, 0);
        }
        __builtin_amdgcn_s_setprio(0);

        // mask (exp2 domain)
        #pragma unroll
        for (int r = 0; r < 16; r++) {
            int bit = (r & 3) + 8*(r >> 2) + 4*hi;
            if ((mv.x >> bit) & 1u) s0[r] = MASKVAL;
            if ((mv.y >> bit) & 1u) s1[r] = MASKVAL;
        }
        // row max (this lane holds half the 64-k row; partner lane^32 the other half)
        float tm[16];
        #pragma unroll
        for (int r = 0; r < 16; r++) tm[r] = fmaxf(s0[r], s1[r]);
        #pragma unroll
        for (int st = 8; st > 0; st >>= 1)
            #pragma unroll
            for (int r = 0; r < st; r++) tm[r] = fmaxf(tm[r], tm[r + st]);
        float rmax = fmaxf(tm[0], __shfl_xor(tm[0], 32));
        float mn = fmaxf(mrun, rmax);
        float alpha = exp2f(mrun - mn);
        mrun = mn;
        // exp + sum
        #pragma unroll
        for (int r = 0; r < 16; r++) {
            s0[r] = exp2f(s0[r] - mn);
            s1[r] = exp2f(s1[r] - mn);
        }
        float ts[16];
        #pragma unroll
        for (int r = 0; r < 16; r++) ts[r] = s0[r] + s1[r];
        #pragma unroll
        for (int st = 8; st > 0; st >>= 1)
            #pragma unroll
            for (int r = 0; r < st; r++) ts[r] = ts[r] + ts[r + st];
        float rsum = ts[0] + __shfl_xor(ts[0], 32);
        lsum = lsum * alpha + rsum;
        #pragma unroll
        for (int r = 0; r < 16; r++) { acc0[r] *= alpha; acc1[r] *= alpha; }

        // P -> bf16 PA fragments (B-operand for PV), via pack2 + permlane32_swap
        bf16x8 pa[4];
        {
            union { u32x4 uv; bf16x8 bv; } cv;
            unsigned x0, y0, x1, y1;
            // slot 0: k 0..15 from s0[0..7]
            x0 = pack2(s0[0], s0[1]); y0 = pack2(s0[4], s0[5]);
            asm volatile("v_permlane32_swap_b32 %0, %1" : "+v"(x0), "+v"(y0));
            x1 = pack2(s0[2], s0[3]); y1 = pack2(s0[6], s0[7]);
            asm volatile("v_permlane32_swap_b32 %0, %1" : "+v"(x1), "+v"(y1));
            cv.uv[0]=x0; cv.uv[1]=x1; cv.uv[2]=y0; cv.uv[3]=y1; pa[0]=cv.bv;
            // slot 1: k 16..31 from s0[8..15]
            x0 = pack2(s0[8], s0[9]);  y0 = pack2(s0[12], s0[13]);
            asm volatile("v_permlane32_swap_b32 %0, %1" : "+v"(x0), "+v"(y0));
            x1 = pack2(s0[10], s0[11]); y1 = pack2(s0[14], s0[15]);
            asm volatile("v_permlane32_swap_b32 %0, %1" : "+v"(x1), "+v"(y1));
            cv.uv[0]=x0; cv.uv[1]=x1; cv.uv[2]=y0; cv.uv[3]=y1; pa[1]=cv.bv;
            // slot 2: k 32..47 from s1[0..7]
            x0 = pack2(s1[0], s1[1]); y0 = pack2(s1[4], s1[5]);
            asm volatile("v_permlane32_swap_b32 %0, %1" : "+v"(x0), "+v"(y0));
            x1 = pack2(s1[2], s1[3]); y1 = pack2(s1[6], s1[7]);
            asm volatile("v_permlane32_swap_b32 %0, %1" : "+v"(x1), "+v"(y1));
            cv.uv[0]=x0; cv.uv[1]=x1; cv.uv[2]=y0; cv.uv[3]=y1; pa[2]=cv.bv;
            // slot 3: k 48..63 from s1[8..15]
            x0 = pack2(s1[8], s1[9]);  y0 = pack2(s1[12], s1[13]);
            asm volatile("v_permlane32_swap_b32 %0, %1" : "+v"(x0), "+v"(y0));
            x1 = pack2(s1[10], s1[11]); y1 = pack2(s1[14], s1[15]);
            asm volatile("v_permlane32_swap_b32 %0, %1" : "+v"(x1), "+v"(y1));
            cv.uv[0]=x0; cv.uv[1]=x1; cv.uv[2]=y0; cv.uv[3]=y1; pa[3]=cv.bv;
        }

        // PV: O^T += V^T . P^T  (8 x mfma_32x32x16)
        __builtin_amdgcn_s_setprio(1);
        #pragma unroll
        for (int ks = 0; ks < 4; ks++) {
            int col = 16*ks + 8*hi;
            int r0 = qc, r1 = 32 + qc;
            bf16x8 v0 = *(const bf16x8*)(vl + r0*64 + (col ^ ((r0 & 7) << 3)));
            bf16x8 v1 = *(const bf16x8*)(vl + r1*64 + (col ^ ((r1 & 7) << 3)));
            acc0 = __builtin_amdgcn_mfma_f32_32x32x16_bf16(v0, pa[ks], acc0, 0, 0, 0);
            acc1 = __builtin_amdgcn_mfma_f32_32x32x16_bf16(v1, pa[ks], acc1, 0, 0, 0);
        }
        __builtin_amdgcn_s_setprio(0);

        __syncthreads();
    }

    float inv = 1.0f / lsum;
    size_t obase = ((size_t)(b * SEQ) + qg) * DM + h * DK;
    #pragma unroll
    for (int gr = 0; gr < 4; gr++) {
        bf16x4 o0, o1;
        #pragma unroll
        for (int jj = 0; jj < 4; jj++) {
            o0[jj] = (bf16_t)(acc0[4*gr + jj] * inv);
            o1[jj] = (bf16_t)(acc1[4*gr + jj] * inv);
        }
        *(bf16x4*)(CTX + obase + gr*8 + hi*4)      = o0;
        *(bf16x4*)(CTX + obase + 32 + gr*8 + hi*4) = o1;
    }
}

// In-place LayerNorm over rows of 768
__global__ __launch_bounds__(256) void ln_kernel(float* __restrict__ out,
        const float* __restrict__ gamma, const float* __restrict__ beta) {
    int w = threadIdx.x >> 6, u = threadIdx.x & 63;
    size_t row = (size_t)blockIdx.x * 4 + w;
    float x[12];
    float s = 0.f;
    #pragma unroll
    for (int i = 0; i < 12; i++) { x[i] = out[row*DM + i*64 + u]; s += x[i]; }
    #pragma unroll
    for (int d = 1; d < 64; d <<= 1) s += __shfl_xor(s, d);
    float mu = s * (1.0f/768.0f);
    float v = 0.f;
    #pragma unroll
    for (int i = 0; i < 12; i++) { float t = x[i] - mu; v += t*t; }
    #pragma unroll
    for (int d = 1; d < 64; d <<= 1) v += __shfl_xor(v, d);
    float rstd = rsqrtf(v * (1.0f/768.0f) + 1e-5f);
    #pragma unroll
    for (int i = 0; i < 12; i++)
        out[row*DM + i*64 + u] = (x[i] - mu) * rstd * gamma[i*64 + u] + beta[i*64 + u];
}

extern "C" void kernel_launch(void* const* d_in, const int* in_sizes, int n_in,
                              void* d_out, int out_size, void* d_ws, size_t ws_size,
                              hipStream_t stream) {
    const float* Q    = (const float*)d_in[0];
    const float* K    = (const float*)d_in[1];
    const float* V    = (const float*)d_in[2];
    const void*  mask = d_in[3];
    const float* WQ   = (const float*)d_in[4];
    const float* bQ   = (const float*)d_in[5];
    const float* WK   = (const float*)d_in[6];
    const float* bK   = (const float*)d_in[7];
    const float* WV   = (const float*)d_in[8];
    const float* bV   = (const float*)d_in[9];
    const float* Wfc  = (const float*)d_in[10];
    const float* bfc  = (const float*)d_in[11];
    const float* gam  = (const float*)d_in[12];
    const float* bet  = (const float*)d_in[13];
    float* out = (float*)d_out;
    char* ws = (char*)d_ws;

    int* flag            = (int*)(ws + OFF_FLAG);
    unsigned int* maskw  = (unsigned int*)(ws + OFF_MASK);
    bf16_t* WT           = (bf16_t*)(ws + OFF_WT);
    bf16_t* XB           = (bf16_t*)(ws + OFF_XB);
    bf16_t* QP           = (bf16_t*)(ws + OFF_QP);
    bf16_t* KP           = (bf16_t*)(ws + OFF_KP);
    bf16_t* VT           = (bf16_t*)(ws + OFF_VT);
    bf16_t* CTX          = XB;   // alias bf16-Q slot (dead after proj z=0)

    detect_mask_kernel<<<1, 64, 0, stream>>>((const unsigned char*)mask, flag);
    pack_mask_kernel<<<2048, 256, 0, stream>>>(mask, flag, maskw);
    xcvt_kernel<<<dim3(3072, 3), 256, 0, stream>>>(Q, K, V, XB);
    wt_cvt_kernel<<<dim3(12, 12, 4), 256, 0, stream>>>(WQ, WK, WV, Wfc, WT);
    proj128_kernel<<<dim3(64, 6, 3), 256, 0, stream>>>(XB, WT, bQ, bK, bV, QP, KP, VT);
    attn_kernel<<<dim3(SEQ/128, HEADS, BATCH), 256, 0, stream>>>(QP, KP, VT, maskw, CTX);
    out128_kernel<<<dim3(64, 6), 256, 0, stream>>>(CTX, WT + (size_t)3*DM*DM, bfc, Q, out);
    ln_kernel<<<2048, 256, 0, stream>>>(out, gam, bet);
}

// Round 4
// 400.736 us; speedup vs baseline: 2.4711x; 1.1197x over previous
//
#include <hip/hip_runtime.h>
#include <stdint.h>

#define DM   768
#define HEADS 12
#define DK    64
#define SEQ  2048
#define BATCH  4

typedef __bf16 bf16_t;
typedef __bf16 bf16x8 __attribute__((ext_vector_type(8)));
typedef __bf16 bf16x4 __attribute__((ext_vector_type(4)));
typedef float  f32x4  __attribute__((ext_vector_type(4)));
typedef float  f32x16 __attribute__((ext_vector_type(16)));
typedef unsigned u32x4 __attribute__((ext_vector_type(4)));

#define LOG2E 1.44269504f
#define MASKVAL (-1.442695e9f)
#define DEFER_THR 8.0f

// ---- workspace layout (bytes), all 256-aligned ----
#define OFF_FLAG 0
#define OFF_MASK 256
#define SZ_MASK  (BATCH*SEQ*(SEQ/32)*4)          // 2 MB packed mask bits
#define OFF_WT   (OFF_MASK + SZ_MASK)
#define SZ_WT1   (DM*DM*2)                       // one bf16 weight (transposed)
#define OFF_XB   (OFF_WT + 4*SZ_WT1)             // bf16 Q,K,V inputs (3 x 12.6MB)
#define SZ_X     (BATCH*SEQ*DM*2)
#define OFF_QP   (OFF_XB + 3*SZ_X)
#define SZ_PROJ  (BATCH*HEADS*SEQ*DK*2)          // 12.6 MB
#define OFF_KP   (OFF_QP + SZ_PROJ)
#define OFF_VT   (OFF_KP + SZ_PROJ)
// CTX aliases XB slot 0 (bf16 Q): dead after proj z=0.

__device__ __forceinline__ void gload_lds16(const bf16_t* g, bf16_t* l) {
    __builtin_amdgcn_global_load_lds((const __attribute__((address_space(1))) unsigned int*)g,
                                     (__attribute__((address_space(3))) unsigned int*)l, 16, 0, 0);
}

__device__ __forceinline__ unsigned pack2(float lo, float hi) {
    union { bf16_t b[2]; unsigned u; } x;
    x.b[0] = (bf16_t)lo; x.b[1] = (bf16_t)hi;
    return x.u;
}

// Detect mask element width: int32 0/1 values have bytes 1,2,3 zero.
__global__ void detect_mask_kernel(const unsigned char* __restrict__ m, int* flag) {
    int u = threadIdx.x;  // 64 threads
    int any = m[4*u+1] | m[4*u+2] | m[4*u+3];
    unsigned long long b = __ballot(any != 0);
    if (u == 0) *flag = (b == 0ULL) ? 1 : 0;
}

// Pack mask (True => masked) into bits.
__global__ void pack_mask_kernel(const void* __restrict__ mraw, const int* __restrict__ flag,
                                 unsigned int* __restrict__ words) {
    const unsigned int total = BATCH*SEQ*SEQ;
    const int is32 = *flag;
    const int* mi = (const int*)mraw;
    const unsigned char* mb = (const unsigned char*)mraw;
    unsigned int stride = gridDim.x * blockDim.x;
    unsigned int lane = threadIdx.x & 63u;
    for (unsigned int e = blockIdx.x * blockDim.x + threadIdx.x; e < total; e += stride) {
        int v = is32 ? (mi[e] != 0) : (mb[e] != 0);
        unsigned long long bal = __ballot(v);
        if ((lane & 31u) == 0u)
            words[e >> 5] = (unsigned int)(bal >> ((lane >> 5) * 32u));
    }
}

// Transpose + convert weights to bf16: W[k][n] f32 -> Wt[n][k] bf16
__global__ void wt_cvt_kernel(const float* __restrict__ W0, const float* __restrict__ W1,
                              const float* __restrict__ W2, const float* __restrict__ W3,
                              bf16_t* __restrict__ dst) {
    const float* W = blockIdx.z == 0 ? W0 : blockIdx.z == 1 ? W1 : blockIdx.z == 2 ? W2 : W3;
    bf16_t* out = dst + (size_t)blockIdx.z * DM * DM;
    __shared__ float tile[64][65];
    int w = threadIdx.x >> 6, u = threadIdx.x & 63;
    int kb = blockIdx.x * 64, nb = blockIdx.y * 64;
    #pragma unroll
    for (int i = 0; i < 16; i++)
        tile[w + 4*i][u] = W[(size_t)(kb + w + 4*i)*DM + nb + u];
    __syncthreads();
    #pragma unroll
    for (int i = 0; i < 16; i++)
        out[(size_t)(nb + w + 4*i)*DM + kb + u] = (bf16_t)tile[u][w + 4*i];
}

// Convert fp32 inputs to bf16
__global__ void xcvt_kernel(const float* __restrict__ Q, const float* __restrict__ K,
                            const float* __restrict__ V, bf16_t* __restrict__ XB) {
    int z = blockIdx.y;
    const float* src = z == 0 ? Q : z == 1 ? K : V;
    bf16_t* dst = XB + (size_t)z * BATCH*SEQ*DM;
    size_t i = ((size_t)blockIdx.x * blockDim.x + threadIdx.x) * 8;
    float4 a = *(const float4*)(src + i);
    float4 b = *(const float4*)(src + i + 4);
    bf16x8 o;
    o[0]=(bf16_t)a.x; o[1]=(bf16_t)a.y; o[2]=(bf16_t)a.z; o[3]=(bf16_t)a.w;
    o[4]=(bf16_t)b.x; o[5]=(bf16_t)b.y; o[6]=(bf16_t)b.z; o[7]=(bf16_t)b.w;
    *(bf16x8*)(dst + i) = o;
}

// m97-style 128x128 tile mainloop
__device__ __forceinline__ void mm_mainloop(const bf16_t* __restrict__ Aptr,
                                            const bf16_t* __restrict__ Bptr,
                                            bf16_t* As, bf16_t* Bs,
                                            f32x4 acc[4][4], int bm, int bn) {
    int tid = threadIdx.x, w = tid >> 6, u = tid & 63, c = u & 15, g = u >> 4;
    int wr = w >> 1, wc = w & 1;
    for (int k0 = 0; k0 < DM; k0 += 64) {
        #pragma unroll
        for (int i = 0; i < 4; i++) {
            int q = i*256 + tid;
            int row = q >> 3, col8 = q & 7;
            gload_lds16(Aptr + (size_t)(bm*128 + row)*DM + k0 + col8*8, As + (i*256 + w*64)*8);
            gload_lds16(Bptr + (size_t)(bn*128 + row)*DM + k0 + col8*8, Bs + (i*256 + w*64)*8);
        }
        __syncthreads();
        #pragma unroll
        for (int kk = 0; kk < 2; kk++) {
            bf16x8 a[4], bfr[4];
            #pragma unroll
            for (int mi = 0; mi < 4; mi++)
                a[mi] = *(const bf16x8*)(As + (wr*64 + mi*16 + c)*64 + kk*32 + g*8);
            #pragma unroll
            for (int ni = 0; ni < 4; ni++)
                bfr[ni] = *(const bf16x8*)(Bs + (wc*64 + ni*16 + c)*64 + kk*32 + g*8);
            #pragma unroll
            for (int mi = 0; mi < 4; mi++)
                #pragma unroll
                for (int ni = 0; ni < 4; ni++)
                    acc[mi][ni] = __builtin_amdgcn_mfma_f32_16x16x32_bf16(a[mi], bfr[ni], acc[mi][ni], 0, 0, 0);
        }
        __syncthreads();
    }
}

// QKV projections: z=0 Q (scaled 0.125*log2e), z=1 K, z=2 V (transposed store)
__global__ __launch_bounds__(256) void proj128_kernel(
        const bf16_t* __restrict__ XB, const bf16_t* __restrict__ WT,
        const float* __restrict__ bQ, const float* __restrict__ bK, const float* __restrict__ bV,
        bf16_t* __restrict__ QP, bf16_t* __restrict__ KP, bf16_t* __restrict__ VT) {
    int z = blockIdx.z;
    const bf16_t* Aptr = XB + (size_t)z * BATCH*SEQ*DM;
    const bf16_t* Bptr = WT + (size_t)z * DM * DM;
    const float* bias = z == 0 ? bQ : z == 1 ? bK : bV;
    float scale = (z == 0) ? 0.125f * LOG2E : 1.0f;
    __shared__ __align__(16) bf16_t As[128*64], Bs[128*64];
    int tid = threadIdx.x, w = tid >> 6, u = tid & 63, c = u & 15, g = u >> 4;
    int wr = w >> 1, wc = w & 1;
    int bm = blockIdx.x, bn = blockIdx.y;
    f32x4 zero = {0.f,0.f,0.f,0.f};
    f32x4 acc[4][4] = {{zero,zero,zero,zero},{zero,zero,zero,zero},
                       {zero,zero,zero,zero},{zero,zero,zero,zero}};
    mm_mainloop(Aptr, Bptr, As, Bs, acc, bm, bn);
    int h = bn*2 + wc;
    #pragma unroll
    for (int ni = 0; ni < 4; ni++) {
        int d = ni*16 + c;
        float bv = bias[h*64 + d];
        if (z < 2) {
            bf16_t* dst = (z == 0) ? QP : KP;
            #pragma unroll
            for (int mi = 0; mi < 4; mi++)
                #pragma unroll
                for (int j = 0; j < 4; j++) {
                    int r = bm*128 + wr*64 + mi*16 + 4*g + j;
                    int bidx = r >> 11, s = r & 2047;
                    dst[(((size_t)bidx*HEADS + h)*SEQ + s)*DK + d] = (bf16_t)((acc[mi][ni][j] + bv)*scale);
                }
        } else {
            #pragma unroll
            for (int mi = 0; mi < 4; mi++) {
                bf16x4 pk;
                #pragma unroll
                for (int j = 0; j < 4; j++) pk[j] = (bf16_t)(acc[mi][ni][j] + bv);
                int r0 = bm*128 + wr*64 + mi*16 + 4*g;
                int bidx = r0 >> 11, s0 = r0 & 2047;
                *(bf16x4*)(VT + (((size_t)bidx*HEADS + h)*DK + d)*SEQ + s0) = pk;
            }
        }
    }
}

// Output projection: out = CTX @ Wfc + bfc + Q (fp32)
__global__ __launch_bounds__(256) void out128_kernel(
        const bf16_t* __restrict__ CTX, const bf16_t* __restrict__ WfcT,
        const float* __restrict__ bfc, const float* __restrict__ Qres, float* __restrict__ out) {
    __shared__ __align__(16) bf16_t As[128*64], Bs[128*64];
    int tid = threadIdx.x, w = tid >> 6, u = tid & 63, c = u & 15, g = u >> 4;
    int wr = w >> 1, wc = w & 1;
    int bm = blockIdx.x, bn = blockIdx.y;
    f32x4 zero = {0.f,0.f,0.f,0.f};
    f32x4 acc[4][4] = {{zero,zero,zero,zero},{zero,zero,zero,zero},
                       {zero,zero,zero,zero},{zero,zero,zero,zero}};
    mm_mainloop(CTX, WfcT, As, Bs, acc, bm, bn);
    #pragma unroll
    for (int ni = 0; ni < 4; ni++) {
        int n = bn*128 + wc*64 + ni*16 + c;
        float bv = bfc[n];
        #pragma unroll
        for (int mi = 0; mi < 4; mi++)
            #pragma unroll
            for (int j = 0; j < 4; j++) {
                int r = bm*128 + wr*64 + mi*16 + 4*g + j;
                out[(size_t)r*DM + n] = acc[mi][ni][j] + bv + Qres[(size_t)r*DM + n];
            }
    }
}

// ---------------- Flash attention, 32x32 MFMA + LDS-staged K/V ----------------
// Block: 4 waves x 32 q-rows. KVBLK=64. K/V double-buffered in LDS (16B XOR
// swizzle). Swapped QK^T; mask via LDS nibble-LUT; defer-max (THR=8, exp2 dom);
// P->bf16 via pack+permlane32_swap.
__global__ __launch_bounds__(256) void attn_kernel(
        const bf16_t* __restrict__ QP, const bf16_t* __restrict__ KP, const bf16_t* __restrict__ VT,
        const unsigned int* __restrict__ maskw, bf16_t* __restrict__ CTX) {
    __shared__ __align__(16) bf16_t kbuf[2][64*64];
    __shared__ __align__(16) bf16_t vbuf[2][64*64];
    __shared__ __align__(16) float lut4[64];
    int tid = threadIdx.x, w = tid >> 6, u = tid & 63;
    int qc = u & 31, hi = u >> 5;
    int b = blockIdx.z, h = blockIdx.y;
    int qg = blockIdx.x * 128 + w * 32 + qc;      // this lane's q row
    size_t bh = (size_t)(b * HEADS + h);
    const bf16_t* qp = QP + bh * SEQ * DK;
    const bf16_t* kp = KP + bh * SEQ * DK;
    const bf16_t* vt = VT + bh * DK * SEQ;
    const unsigned int* mwq = maskw + ((size_t)b * SEQ + qg) * (SEQ/32);

    // mask LUT: entry e (4 bits) -> 4 floats {0 or MASKVAL}
    if (tid < 64) lut4[tid] = (((tid >> 2) >> (tid & 3)) & 1) ? MASKVAL : 0.f;

    // persistent Q fragments (B-operand)
    bf16x8 qf[4];
    #pragma unroll
    for (int t = 0; t < 4; t++)
        qf[t] = *(const bf16x8*)(qp + (size_t)qg*DK + 16*t + 8*hi);

    int sr = tid >> 3, scc = tid & 7;

    f32x16 zz = {0,0,0,0,0,0,0,0,0,0,0,0,0,0,0,0};
    f32x16 acc0 = zz, acc1 = zz;
    float mrun = -3e38f, lsum = 0.f;

    // prologue: stage tile 0 into buf 0
    #pragma unroll
    for (int i = 0; i < 2; i++) {
        int r = i*32 + sr;
        int gc = (scc ^ (r & 7)) << 3;
        gload_lds16(kp + (size_t)r*DK + gc,       &kbuf[0][0] + i*2048 + tid*8);
        gload_lds16(vt + (size_t)r*SEQ + 0 + gc,  &vbuf[0][0] + i*2048 + tid*8);
    }
    uint2 mv = *(const uint2*)(mwq);
    __syncthreads();

    for (int kt = 0; kt < SEQ/64; kt++) {
        int kb = kt * 64;
        int cur = kt & 1;
        uint2 mv_next;
        // prefetch next mask words + stage next K/V tile
        if (kt + 1 < SEQ/64) {
            mv_next = *(const uint2*)(mwq + ((kb + 64) >> 5));
            int nkb = kb + 64;
            #pragma unroll
            for (int i = 0; i < 2; i++) {
                int r = i*32 + sr;
                int gc = (scc ^ (r & 7)) << 3;
                gload_lds16(kp + (size_t)(nkb + r)*DK + gc, &kbuf[cur^1][0] + i*2048 + tid*8);
                gload_lds16(vt + (size_t)r*SEQ + nkb + gc,  &vbuf[cur^1][0] + i*2048 + tid*8);
            }
        }
        const bf16_t* kl = &kbuf[cur][0];
        const bf16_t* vl = &vbuf[cur][0];

        // mask add-values via LDS LUT (issued early; latency hides under QK^T)
        f32x4 am0[4], am1[4];
        #pragma unroll
        for (int j = 0; j < 4; j++) {
            am0[j] = *(const f32x4*)&lut4[((mv.x >> (8*j + 4*hi)) & 0xFu) * 4];
            am1[j] = *(const f32x4*)&lut4[((mv.y >> (8*j + 4*hi)) & 0xFu) * 4];
        }

        // QK^T (S^T): 8 x mfma_32x32x16
        f32x16 s0 = zz, s1 = zz;
        __builtin_amdgcn_s_setprio(1);
        #pragma unroll
        for (int t = 0; t < 4; t++) {
            int col = (16*t + 8*hi);
            int r0 = qc, r1 = 32 + qc;
            bf16x8 k0 = *(const bf16x8*)(kl + r0*64 + (col ^ ((r0 & 7) << 3)));
            bf16x8 k1 = *(const bf16x8*)(kl + r1*64 + (col ^ ((r1 & 7) << 3)));
            s0 = __builtin_amdgcn_mfma_f32_32x32x16_bf16(k0, qf[t], s0, 0, 0, 0);
            s1 = __builtin_amdgcn_mfma_f32_32x32x16_bf16(k1, qf[t], s1, 0, 0, 0);
        }
        __builtin_amdgcn_s_setprio(0);

        // apply mask adds
        #pragma unroll
        for (int j = 0; j < 4; j++)
            #pragma unroll
            for (int i = 0; i < 4; i++) {
                s0[4*j + i] += am0[j][i];
                s1[4*j + i] += am1[j][i];
            }

        // per-lane tile max (31 fmax)
        float tmx[16];
        #pragma unroll
        for (int r = 0; r < 16; r++) tmx[r] = fmaxf(s0[r], s1[r]);
        #pragma unroll
        for (int st = 8; st > 0; st >>= 1)
            #pragma unroll
            for (int r = 0; r < st; r++) tmx[r] = fmaxf(tmx[r], tmx[r + st]);
        float tm = tmx[0];

        // defer-max: rescale only if some row grew past mrun + THR
        if (!__all(tm <= mrun + DEFER_THR)) {
            float rmax = fmaxf(tm, __shfl_xor(tm, 32));
            float mn = fmaxf(mrun, rmax);
            float alpha = __builtin_amdgcn_exp2f(mrun - mn);
            mrun = mn;
            lsum *= alpha;
            acc0 *= alpha;
            acc1 *= alpha;
        }

        // exp2 (p bounded by 2^THR)
        #pragma unroll
        for (int r = 0; r < 16; r++) {
            s0[r] = __builtin_amdgcn_exp2f(s0[r] - mrun);
            s1[r] = __builtin_amdgcn_exp2f(s1[r] - mrun);
        }
        // sum
        float sm[16];
        #pragma unroll
        for (int r = 0; r < 16; r++) sm[r] = s0[r] + s1[r];
        #pragma unroll
        for (int st = 8; st > 0; st >>= 1)
            #pragma unroll
            for (int r = 0; r < st; r++) sm[r] = sm[r] + sm[r + st];
        lsum += sm[0] + __shfl_xor(sm[0], 32);

        // P -> bf16 PA fragments via pack2 + permlane32_swap
        bf16x8 pa[4];
        {
            union { u32x4 uv; bf16x8 bv; } cv;
            unsigned x0, y0, x1, y1;
            x0 = pack2(s0[0], s0[1]); y0 = pack2(s0[4], s0[5]);
            asm volatile("v_permlane32_swap_b32 %0, %1" : "+v"(x0), "+v"(y0));
            x1 = pack2(s0[2], s0[3]); y1 = pack2(s0[6], s0[7]);
            asm volatile("v_permlane32_swap_b32 %0, %1" : "+v"(x1), "+v"(y1));
            cv.uv[0]=x0; cv.uv[1]=x1; cv.uv[2]=y0; cv.uv[3]=y1; pa[0]=cv.bv;
            x0 = pack2(s0[8], s0[9]);  y0 = pack2(s0[12], s0[13]);
            asm volatile("v_permlane32_swap_b32 %0, %1" : "+v"(x0), "+v"(y0));
            x1 = pack2(s0[10], s0[11]); y1 = pack2(s0[14], s0[15]);
            asm volatile("v_permlane32_swap_b32 %0, %1" : "+v"(x1), "+v"(y1));
            cv.uv[0]=x0; cv.uv[1]=x1; cv.uv[2]=y0; cv.uv[3]=y1; pa[1]=cv.bv;
            x0 = pack2(s1[0], s1[1]); y0 = pack2(s1[4], s1[5]);
            asm volatile("v_permlane32_swap_b32 %0, %1" : "+v"(x0), "+v"(y0));
            x1 = pack2(s1[2], s1[3]); y1 = pack2(s1[6], s1[7]);
            asm volatile("v_permlane32_swap_b32 %0, %1" : "+v"(x1), "+v"(y1));
            cv.uv[0]=x0; cv.uv[1]=x1; cv.uv[2]=y0; cv.uv[3]=y1; pa[2]=cv.bv;
            x0 = pack2(s1[8], s1[9]);  y0 = pack2(s1[12], s1[13]);
            asm volatile("v_permlane32_swap_b32 %0, %1" : "+v"(x0), "+v"(y0));
            x1 = pack2(s1[10], s1[11]); y1 = pack2(s1[14], s1[15]);
            asm volatile("v_permlane32_swap_b32 %0, %1" : "+v"(x1), "+v"(y1));
            cv.uv[0]=x0; cv.uv[1]=x1; cv.uv[2]=y0; cv.uv[3]=y1; pa[3]=cv.bv;
        }

        // PV: O^T += V^T . P^T
        __builtin_amdgcn_s_setprio(1);
        #pragma unroll
        for (int ks = 0; ks < 4; ks++) {
            int col = 16*ks + 8*hi;
            int r0 = qc, r1 = 32 + qc;
            bf16x8 v0 = *(const bf16x8*)(vl + r0*64 + (col ^ ((r0 & 7) << 3)));
            bf16x8 v1 = *(const bf16x8*)(vl + r1*64 + (col ^ ((r1 & 7) << 3)));
            acc0 = __builtin_amdgcn_mfma_f32_32x32x16_bf16(v0, pa[ks], acc0, 0, 0, 0);
            acc1 = __builtin_amdgcn_mfma_f32_32x32x16_bf16(v1, pa[ks], acc1, 0, 0, 0);
        }
        __builtin_amdgcn_s_setprio(0);

        __syncthreads();
        mv = mv_next;
    }

    float inv = 1.0f / lsum;
    size_t obase = ((size_t)(b * SEQ) + qg) * DM + h * DK;
    #pragma unroll
    for (int gr = 0; gr < 4; gr++) {
        bf16x4 o0, o1;
        #pragma unroll
        for (int jj = 0; jj < 4; jj++) {
            o0[jj] = (bf16_t)(acc0[4*gr + jj] * inv);
            o1[jj] = (bf16_t)(acc1[4*gr + jj] * inv);
        }
        *(bf16x4*)(CTX + obase + gr*8 + hi*4)      = o0;
        *(bf16x4*)(CTX + obase + 32 + gr*8 + hi*4) = o1;
    }
}

// In-place LayerNorm over rows of 768
__global__ __launch_bounds__(256) void ln_kernel(float* __restrict__ out,
        const float* __restrict__ gamma, const float* __restrict__ beta) {
    int w = threadIdx.x >> 6, u = threadIdx.x & 63;
    size_t row = (size_t)blockIdx.x * 4 + w;
    float x[12];
    float s = 0.f;
    #pragma unroll
    for (int i = 0; i < 12; i++) { x[i] = out[row*DM + i*64 + u]; s += x[i]; }
    #pragma unroll
    for (int d = 1; d < 64; d <<= 1) s += __shfl_xor(s, d);
    float mu = s * (1.0f/768.0f);
    float v = 0.f;
    #pragma unroll
    for (int i = 0; i < 12; i++) { float t = x[i] - mu; v += t*t; }
    #pragma unroll
    for (int d = 1; d < 64; d <<= 1) v += __shfl_xor(v, d);
    float rstd = rsqrtf(v * (1.0f/768.0f) + 1e-5f);
    #pragma unroll
    for (int i = 0; i < 12; i++)
        out[row*DM + i*64 + u] = (x[i] - mu) * rstd * gamma[i*64 + u] + beta[i*64 + u];
}

extern "C" void kernel_launch(void* const* d_in, const int* in_sizes, int n_in,
                              void* d_out, int out_size, void* d_ws, size_t ws_size,
                              hipStream_t stream) {
    const float* Q    = (const float*)d_in[0];
    const float* K    = (const float*)d_in[1];
    const float* V    = (const float*)d_in[2];
    const void*  mask = d_in[3];
    const float* WQ   = (const float*)d_in[4];
    const float* bQ   = (const float*)d_in[5];
    const float* WK   = (const float*)d_in[6];
    const float* bK   = (const float*)d_in[7];
    const float* WV   = (const float*)d_in[8];
    const float* bV   = (const float*)d_in[9];
    const float* Wfc  = (const float*)d_in[10];
    const float* bfc  = (const float*)d_in[11];
    const float* gam  = (const float*)d_in[12];
    const float* bet  = (const float*)d_in[13];
    float* out = (float*)d_out;
    char* ws = (char*)d_ws;

    int* flag            = (int*)(ws + OFF_FLAG);
    unsigned int* maskw  = (unsigned int*)(ws + OFF_MASK);
    bf16_t* WT           = (bf16_t*)(ws + OFF_WT);
    bf16_t* XB           = (bf16_t*)(ws + OFF_XB);
    bf16_t* QP           = (bf16_t*)(ws + OFF_QP);
    bf16_t* KP           = (bf16_t*)(ws + OFF_KP);
    bf16_t* VT           = (bf16_t*)(ws + OFF_VT);
    bf16_t* CTX          = XB;   // alias bf16-Q slot (dead after proj z=0)

    detect_mask_kernel<<<1, 64, 0, stream>>>((const unsigned char*)mask, flag);
    pack_mask_kernel<<<2048, 256, 0, stream>>>(mask, flag, maskw);
    xcvt_kernel<<<dim3(3072, 3), 256, 0, stream>>>(Q, K, V, XB);
    wt_cvt_kernel<<<dim3(12, 12, 4), 256, 0, stream>>>(WQ, WK, WV, Wfc, WT);
    proj128_kernel<<<dim3(64, 6, 3), 256, 0, stream>>>(XB, WT, bQ, bK, bV, QP, KP, VT);
    attn_kernel<<<dim3(SEQ/128, HEADS, BATCH), 256, 0, stream>>>(QP, KP, VT, maskw, CTX);
    out128_kernel<<<dim3(64, 6), 256, 0, stream>>>(CTX, WT + (size_t)3*DM*DM, bfc, Q, out);
    ln_kernel<<<2048, 256, 0, stream>>>(out, gam, bet);
}

// Round 5
// 396.266 us; speedup vs baseline: 2.4990x; 1.0113x over previous
//
#include <hip/hip_runtime.h>
#include <stdint.h>

#define DM   768
#define HEADS 12
#define DK    64
#define SEQ  2048
#define BATCH  4

typedef __bf16 bf16_t;
typedef __bf16 bf16x8 __attribute__((ext_vector_type(8)));
typedef __bf16 bf16x4 __attribute__((ext_vector_type(4)));
typedef float  f32x4  __attribute__((ext_vector_type(4)));
typedef float  f32x16 __attribute__((ext_vector_type(16)));
typedef unsigned u32x4 __attribute__((ext_vector_type(4)));

#define LOG2E 1.44269504f
#define MASKVAL (-1.442695e9f)
#define DEFER_THR 8.0f

// ---- workspace layout (bytes), all 256-aligned ----
#define OFF_FLAG 0
#define OFF_MASK 256
#define SZ_MASK  (BATCH*SEQ*(SEQ/32)*4)          // 2 MB packed mask bits
#define OFF_WT   (OFF_MASK + SZ_MASK)
#define SZ_WT1   (DM*DM*2)                       // one bf16 weight (transposed)
#define OFF_XB   (OFF_WT + 4*SZ_WT1)             // bf16 Q,K,V inputs (3 x 12.6MB)
#define SZ_X     (BATCH*SEQ*DM*2)
#define OFF_QP   (OFF_XB + 3*SZ_X)
#define SZ_PROJ  (BATCH*HEADS*SEQ*DK*2)          // 12.6 MB
#define OFF_KP   (OFF_QP + SZ_PROJ)
#define OFF_VT   (OFF_KP + SZ_PROJ)
#define OFF_ML   (OFF_VT + SZ_PROJ)              // 2 x [B][H][S] x {m,l} f32
#define SZ_ML    (2*BATCH*HEADS*SEQ*2*4)
// OP (split-kv partial O, bf16, 2 x [B][H][S][DK]) aliases XB slots 1,2 (dead after proj)
// CTX aliases XB slot 0 (dead after proj z=0)

__device__ __forceinline__ void gload_lds16(const bf16_t* g, bf16_t* l) {
    __builtin_amdgcn_global_load_lds((const __attribute__((address_space(1))) unsigned int*)g,
                                     (__attribute__((address_space(3))) unsigned int*)l, 16, 0, 0);
}

__device__ __forceinline__ unsigned pack2(float lo, float hi) {
    union { bf16_t b[2]; unsigned u; } x;
    x.b[0] = (bf16_t)lo; x.b[1] = (bf16_t)hi;
    return x.u;
}

// Detect mask element width: int32 0/1 values have bytes 1,2,3 zero.
__global__ void detect_mask_kernel(const unsigned char* __restrict__ m, int* flag) {
    int u = threadIdx.x;  // 64 threads
    int any = m[4*u+1] | m[4*u+2] | m[4*u+3];
    unsigned long long b = __ballot(any != 0);
    if (u == 0) *flag = (b == 0ULL) ? 1 : 0;
}

// Pack mask (True => masked) into bits.
__global__ void pack_mask_kernel(const void* __restrict__ mraw, const int* __restrict__ flag,
                                 unsigned int* __restrict__ words) {
    const unsigned int total = BATCH*SEQ*SEQ;
    const int is32 = *flag;
    const int* mi = (const int*)mraw;
    const unsigned char* mb = (const unsigned char*)mraw;
    unsigned int stride = gridDim.x * blockDim.x;
    unsigned int lane = threadIdx.x & 63u;
    for (unsigned int e = blockIdx.x * blockDim.x + threadIdx.x; e < total; e += stride) {
        int v = is32 ? (mi[e] != 0) : (mb[e] != 0);
        unsigned long long bal = __ballot(v);
        if ((lane & 31u) == 0u)
            words[e >> 5] = (unsigned int)(bal >> ((lane >> 5) * 32u));
    }
}

// Transpose + convert weights to bf16: W[k][n] f32 -> Wt[n][k] bf16
__global__ void wt_cvt_kernel(const float* __restrict__ W0, const float* __restrict__ W1,
                              const float* __restrict__ W2, const float* __restrict__ W3,
                              bf16_t* __restrict__ dst) {
    const float* W = blockIdx.z == 0 ? W0 : blockIdx.z == 1 ? W1 : blockIdx.z == 2 ? W2 : W3;
    bf16_t* out = dst + (size_t)blockIdx.z * DM * DM;
    __shared__ float tile[64][65];
    int w = threadIdx.x >> 6, u = threadIdx.x & 63;
    int kb = blockIdx.x * 64, nb = blockIdx.y * 64;
    #pragma unroll
    for (int i = 0; i < 16; i++)
        tile[w + 4*i][u] = W[(size_t)(kb + w + 4*i)*DM + nb + u];
    __syncthreads();
    #pragma unroll
    for (int i = 0; i < 16; i++)
        out[(size_t)(nb + w + 4*i)*DM + kb + u] = (bf16_t)tile[u][w + 4*i];
}

// Convert fp32 inputs to bf16
__global__ void xcvt_kernel(const float* __restrict__ Q, const float* __restrict__ K,
                            const float* __restrict__ V, bf16_t* __restrict__ XB) {
    int z = blockIdx.y;
    const float* src = z == 0 ? Q : z == 1 ? K : V;
    bf16_t* dst = XB + (size_t)z * BATCH*SEQ*DM;
    size_t i = ((size_t)blockIdx.x * blockDim.x + threadIdx.x) * 8;
    float4 a = *(const float4*)(src + i);
    float4 b = *(const float4*)(src + i + 4);
    bf16x8 o;
    o[0]=(bf16_t)a.x; o[1]=(bf16_t)a.y; o[2]=(bf16_t)a.z; o[3]=(bf16_t)a.w;
    o[4]=(bf16_t)b.x; o[5]=(bf16_t)b.y; o[6]=(bf16_t)b.z; o[7]=(bf16_t)b.w;
    *(bf16x8*)(dst + i) = o;
}

// 128x96 tile mainloop (BM=128, BN=96), 4 waves as 2m x 2n
__device__ __forceinline__ void mm_mainloop96(const bf16_t* __restrict__ Aptr,
                                              const bf16_t* __restrict__ Bptr,
                                              bf16_t* As, bf16_t* Bs,
                                              f32x4 acc[4][3], int bm, int bn) {
    int tid = threadIdx.x, w = tid >> 6, u = tid & 63, c = u & 15, g = u >> 4;
    int wr = w & 1, wc = w >> 1;
    for (int k0 = 0; k0 < DM; k0 += 64) {
        #pragma unroll
        for (int i = 0; i < 4; i++) {
            int q = i*256 + tid;
            int row = q >> 3, col8 = q & 7;
            gload_lds16(Aptr + (size_t)(bm*128 + row)*DM + k0 + col8*8, As + (i*256 + w*64)*8);
        }
        #pragma unroll
        for (int i = 0; i < 3; i++) {
            int q = i*256 + tid;
            int row = q >> 3, col8 = q & 7;
            gload_lds16(Bptr + (size_t)(bn*96 + row)*DM + k0 + col8*8, Bs + (i*256 + w*64)*8);
        }
        __syncthreads();
        #pragma unroll
        for (int kk = 0; kk < 2; kk++) {
            bf16x8 a[4], bfr[3];
            #pragma unroll
            for (int mi = 0; mi < 4; mi++)
                a[mi] = *(const bf16x8*)(As + (wr*64 + mi*16 + c)*64 + kk*32 + g*8);
            #pragma unroll
            for (int ni = 0; ni < 3; ni++)
                bfr[ni] = *(const bf16x8*)(Bs + (wc*48 + ni*16 + c)*64 + kk*32 + g*8);
            #pragma unroll
            for (int mi = 0; mi < 4; mi++)
                #pragma unroll
                for (int ni = 0; ni < 3; ni++)
                    acc[mi][ni] = __builtin_amdgcn_mfma_f32_16x16x32_bf16(a[mi], bfr[ni], acc[mi][ni], 0, 0, 0);
        }
        __syncthreads();
    }
}

// QKV projections: z=0 Q (scaled 0.125*log2e), z=1 K, z=2 V (transposed store)
__global__ __launch_bounds__(256) void proj96_kernel(
        const bf16_t* __restrict__ XB, const bf16_t* __restrict__ WT,
        const float* __restrict__ bQ, const float* __restrict__ bK, const float* __restrict__ bV,
        bf16_t* __restrict__ QP, bf16_t* __restrict__ KP, bf16_t* __restrict__ VT) {
    int z = blockIdx.z;
    const bf16_t* Aptr = XB + (size_t)z * BATCH*SEQ*DM;
    const bf16_t* Bptr = WT + (size_t)z * DM * DM;
    const float* bias = z == 0 ? bQ : z == 1 ? bK : bV;
    float scale = (z == 0) ? 0.125f * LOG2E : 1.0f;
    __shared__ __align__(16) bf16_t As[128*64], Bs[96*64];
    int tid = threadIdx.x, w = tid >> 6, u = tid & 63, c = u & 15, g = u >> 4;
    int wr = w & 1, wc = w >> 1;
    int bm = blockIdx.x, bn = blockIdx.y;
    f32x4 zero = {0.f,0.f,0.f,0.f};
    f32x4 acc[4][3] = {{zero,zero,zero},{zero,zero,zero},{zero,zero,zero},{zero,zero,zero}};
    mm_mainloop96(Aptr, Bptr, As, Bs, acc, bm, bn);
    #pragma unroll
    for (int ni = 0; ni < 3; ni++) {
        int n = bn*96 + wc*48 + ni*16 + c;
        int h = n >> 6, d = n & 63;
        float bv = bias[n];
        if (z < 2) {
            bf16_t* dst = (z == 0) ? QP : KP;
            #pragma unroll
            for (int mi = 0; mi < 4; mi++)
                #pragma unroll
                for (int j = 0; j < 4; j++) {
                    int r = bm*128 + wr*64 + mi*16 + 4*g + j;
                    int bidx = r >> 11, s = r & 2047;
                    dst[(((size_t)bidx*HEADS + h)*SEQ + s)*DK + d] = (bf16_t)((acc[mi][ni][j] + bv)*scale);
                }
        } else {
            #pragma unroll
            for (int mi = 0; mi < 4; mi++) {
                bf16x4 pk;
                #pragma unroll
                for (int j = 0; j < 4; j++) pk[j] = (bf16_t)(acc[mi][ni][j] + bv);
                int r0 = bm*128 + wr*64 + mi*16 + 4*g;
                int bidx = r0 >> 11, s0 = r0 & 2047;
                *(bf16x4*)(VT + (((size_t)bidx*HEADS + h)*DK + d)*SEQ + s0) = pk;
            }
        }
    }
}

// Output projection: out = CTX @ Wfc + bfc + Q (fp32)
__global__ __launch_bounds__(256) void out96_kernel(
        const bf16_t* __restrict__ CTX, const bf16_t* __restrict__ WfcT,
        const float* __restrict__ bfc, const float* __restrict__ Qres, float* __restrict__ out) {
    __shared__ __align__(16) bf16_t As[128*64], Bs[96*64];
    int tid = threadIdx.x, w = tid >> 6, u = tid & 63, c = u & 15, g = u >> 4;
    int wr = w & 1, wc = w >> 1;
    int bm = blockIdx.x, bn = blockIdx.y;
    f32x4 zero = {0.f,0.f,0.f,0.f};
    f32x4 acc[4][3] = {{zero,zero,zero},{zero,zero,zero},{zero,zero,zero},{zero,zero,zero}};
    mm_mainloop96(CTX, WfcT, As, Bs, acc, bm, bn);
    #pragma unroll
    for (int ni = 0; ni < 3; ni++) {
        int n = bn*96 + wc*48 + ni*16 + c;
        float bv = bfc[n];
        #pragma unroll
        for (int mi = 0; mi < 4; mi++)
            #pragma unroll
            for (int j = 0; j < 4; j++) {
                int r = bm*128 + wr*64 + mi*16 + 4*g + j;
                out[(size_t)r*DM + n] = acc[mi][ni][j] + bv + Qres[(size_t)r*DM + n];
            }
    }
}

// ---------------- Flash attention, split-KV 2-way ----------------
// Block: 4 waves x 32 q-rows = 128 q, KV range = split*1024..+1024 (16 tiles).
// K/V double-buffered LDS (16B XOR swizzle); swapped QK^T; LDS nibble-LUT mask;
// defer-max; pack+permlane P->bf16. Writes unnormalized O^T (bf16) + (m,l).
__global__ __launch_bounds__(256) void attn_kernel(
        const bf16_t* __restrict__ QP, const bf16_t* __restrict__ KP, const bf16_t* __restrict__ VT,
        const unsigned int* __restrict__ maskw, bf16_t* __restrict__ OP, float* __restrict__ ML) {
    __shared__ __align__(16) bf16_t kbuf[2][64*64];
    __shared__ __align__(16) bf16_t vbuf[2][64*64];
    __shared__ __align__(16) float lut4[64];
    int tid = threadIdx.x, w = tid >> 6, u = tid & 63;
    int qc = u & 31, hi = u >> 5;
    int sp = blockIdx.z & 1, b = blockIdx.z >> 1, h = blockIdx.y;
    int kvbase = sp << 10;
    int qg = blockIdx.x * 128 + w * 32 + qc;      // this lane's q row
    size_t bh = (size_t)(b * HEADS + h);
    const bf16_t* qp = QP + bh * SEQ * DK;
    const bf16_t* kp = KP + bh * SEQ * DK;
    const bf16_t* vt = VT + bh * DK * SEQ;
    const unsigned int* mwq = maskw + ((size_t)b * SEQ + qg) * (SEQ/32);

    // mask LUT: entry e (4 bits) -> 4 floats {0 or MASKVAL}
    if (tid < 64) lut4[tid] = (((tid >> 2) >> (tid & 3)) & 1) ? MASKVAL : 0.f;

    // persistent Q fragments (B-operand)
    bf16x8 qf[4];
    #pragma unroll
    for (int t = 0; t < 4; t++)
        qf[t] = *(const bf16x8*)(qp + (size_t)qg*DK + 16*t + 8*hi);

    int sr = tid >> 3, scc = tid & 7;

    f32x16 zz = {0,0,0,0,0,0,0,0,0,0,0,0,0,0,0,0};
    f32x16 acc0 = zz, acc1 = zz;
    float mrun = -16384.0f, lsum = 0.f;

    // prologue: stage tile 0 into buf 0
    #pragma unroll
    for (int i = 0; i < 2; i++) {
        int r = i*32 + sr;
        int gc = (scc ^ (r & 7)) << 3;
        gload_lds16(kp + (size_t)(kvbase + r)*DK + gc,   &kbuf[0][0] + i*2048 + tid*8);
        gload_lds16(vt + (size_t)r*SEQ + kvbase + gc,    &vbuf[0][0] + i*2048 + tid*8);
    }
    uint2 mv = *(const uint2*)(mwq + (kvbase >> 5));
    __syncthreads();

    for (int kt = 0; kt < 16; kt++) {
        int kb = kvbase + kt * 64;
        int cur = kt & 1;
        uint2 mv_next = mv;
        // prefetch next mask words + stage next K/V tile
        if (kt + 1 < 16) {
            mv_next = *(const uint2*)(mwq + ((kb + 64) >> 5));
            int nkb = kb + 64;
            #pragma unroll
            for (int i = 0; i < 2; i++) {
                int r = i*32 + sr;
                int gc = (scc ^ (r & 7)) << 3;
                gload_lds16(kp + (size_t)(nkb + r)*DK + gc, &kbuf[cur^1][0] + i*2048 + tid*8);
                gload_lds16(vt + (size_t)r*SEQ + nkb + gc,  &vbuf[cur^1][0] + i*2048 + tid*8);
            }
        }
        const bf16_t* kl = &kbuf[cur][0];
        const bf16_t* vl = &vbuf[cur][0];

        // mask add-values via LDS LUT (issued early; latency hides under QK^T)
        f32x4 am0[4], am1[4];
        #pragma unroll
        for (int j = 0; j < 4; j++) {
            am0[j] = *(const f32x4*)&lut4[((mv.x >> (8*j + 4*hi)) & 0xFu) * 4];
            am1[j] = *(const f32x4*)&lut4[((mv.y >> (8*j + 4*hi)) & 0xFu) * 4];
        }

        // QK^T (S^T): 8 x mfma_32x32x16
        f32x16 s0 = zz, s1 = zz;
        __builtin_amdgcn_s_setprio(1);
        #pragma unroll
        for (int t = 0; t < 4; t++) {
            int col = (16*t + 8*hi);
            int r0 = qc, r1 = 32 + qc;
            bf16x8 k0 = *(const bf16x8*)(kl + r0*64 + (col ^ ((r0 & 7) << 3)));
            bf16x8 k1 = *(const bf16x8*)(kl + r1*64 + (col ^ ((r1 & 7) << 3)));
            s0 = __builtin_amdgcn_mfma_f32_32x32x16_bf16(k0, qf[t], s0, 0, 0, 0);
            s1 = __builtin_amdgcn_mfma_f32_32x32x16_bf16(k1, qf[t], s1, 0, 0, 0);
        }
        __builtin_amdgcn_s_setprio(0);

        // apply mask adds
        #pragma unroll
        for (int j = 0; j < 4; j++)
            #pragma unroll
            for (int i = 0; i < 4; i++) {
                s0[4*j + i] += am0[j][i];
                s1[4*j + i] += am1[j][i];
            }

        // per-lane tile max, grouped 4-way for v_max3 fusion
        float q8[8];
        #pragma unroll
        for (int r = 0; r < 8; r++)
            q8[r] = fmaxf(fmaxf(s0[r], s0[r+8]), fmaxf(s1[r], s1[r+8]));
        float q4a = fmaxf(fmaxf(q8[0], q8[1]), fmaxf(q8[2], q8[3]));
        float q4b = fmaxf(fmaxf(q8[4], q8[5]), fmaxf(q8[6], q8[7]));
        float tm = fmaxf(q4a, q4b);

        // defer-max: rescale only if some row grew past mrun + THR
        if (!__all(tm <= mrun + DEFER_THR)) {
            float rmax = fmaxf(tm, __shfl_xor(tm, 32));
            float mn = fmaxf(mrun, rmax);
            float alpha = __builtin_amdgcn_exp2f(mrun - mn);
            mrun = mn;
            lsum *= alpha;
            acc0 *= alpha;
            acc1 *= alpha;
        }

        // exp2 (p bounded by 2^THR)
        #pragma unroll
        for (int r = 0; r < 16; r++) {
            s0[r] = __builtin_amdgcn_exp2f(s0[r] - mrun);
            s1[r] = __builtin_amdgcn_exp2f(s1[r] - mrun);
        }
        // sum (vector add first; may pack)
        f32x16 sv = s0 + s1;
        float a8[8];
        #pragma unroll
        for (int r = 0; r < 8; r++) a8[r] = sv[r] + sv[r+8];
        float a4a = (a8[0] + a8[1]) + (a8[2] + a8[3]);
        float a4b = (a8[4] + a8[5]) + (a8[6] + a8[7]);
        float rsum = a4a + a4b;
        lsum += rsum + __shfl_xor(rsum, 32);

        // P -> bf16 PA fragments via pack2 + permlane32_swap
        bf16x8 pa[4];
        {
            union { u32x4 uv; bf16x8 bv; } cv;
            unsigned x0, y0, x1, y1;
            x0 = pack2(s0[0], s0[1]); y0 = pack2(s0[4], s0[5]);
            asm volatile("v_permlane32_swap_b32 %0, %1" : "+v"(x0), "+v"(y0));
            x1 = pack2(s0[2], s0[3]); y1 = pack2(s0[6], s0[7]);
            asm volatile("v_permlane32_swap_b32 %0, %1" : "+v"(x1), "+v"(y1));
            cv.uv[0]=x0; cv.uv[1]=x1; cv.uv[2]=y0; cv.uv[3]=y1; pa[0]=cv.bv;
            x0 = pack2(s0[8], s0[9]);  y0 = pack2(s0[12], s0[13]);
            asm volatile("v_permlane32_swap_b32 %0, %1" : "+v"(x0), "+v"(y0));
            x1 = pack2(s0[10], s0[11]); y1 = pack2(s0[14], s0[15]);
            asm volatile("v_permlane32_swap_b32 %0, %1" : "+v"(x1), "+v"(y1));
            cv.uv[0]=x0; cv.uv[1]=x1; cv.uv[2]=y0; cv.uv[3]=y1; pa[1]=cv.bv;
            x0 = pack2(s1[0], s1[1]); y0 = pack2(s1[4], s1[5]);
            asm volatile("v_permlane32_swap_b32 %0, %1" : "+v"(x0), "+v"(y0));
            x1 = pack2(s1[2], s1[3]); y1 = pack2(s1[6], s1[7]);
            asm volatile("v_permlane32_swap_b32 %0, %1" : "+v"(x1), "+v"(y1));
            cv.uv[0]=x0; cv.uv[1]=x1; cv.uv[2]=y0; cv.uv[3]=y1; pa[2]=cv.bv;
            x0 = pack2(s1[8], s1[9]);  y0 = pack2(s1[12], s1[13]);
            asm volatile("v_permlane32_swap_b32 %0, %1" : "+v"(x0), "+v"(y0));
            x1 = pack2(s1[10], s1[11]); y1 = pack2(s1[14], s1[15]);
            asm volatile("v_permlane32_swap_b32 %0, %1" : "+v"(x1), "+v"(y1));
            cv.uv[0]=x0; cv.uv[1]=x1; cv.uv[2]=y0; cv.uv[3]=y1; pa[3]=cv.bv;
        }

        // PV: O^T += V^T . P^T
        __builtin_amdgcn_s_setprio(1);
        #pragma unroll
        for (int ks = 0; ks < 4; ks++) {
            int col = 16*ks + 8*hi;
            int r0 = qc, r1 = 32 + qc;
            bf16x8 v0 = *(const bf16x8*)(vl + r0*64 + (col ^ ((r0 & 7) << 3)));
            bf16x8 v1 = *(const bf16x8*)(vl + r1*64 + (col ^ ((r1 & 7) << 3)));
            acc0 = __builtin_amdgcn_mfma_f32_32x32x16_bf16(v0, pa[ks], acc0, 0, 0, 0);
            acc1 = __builtin_amdgcn_mfma_f32_32x32x16_bf16(v1, pa[ks], acc1, 0, 0, 0);
        }
        __builtin_amdgcn_s_setprio(0);

        __syncthreads();
        mv = mv_next;
    }

    // write unnormalized partial O^T (bf16) + (m,l)
    size_t prow = ((size_t)(sp * BATCH + b) * HEADS + h) * SEQ + qg;
    #pragma unroll
    for (int gr = 0; gr < 4; gr++) {
        bf16x4 o0, o1;
        #pragma unroll
        for (int jj = 0; jj < 4; jj++) {
            o0[jj] = (bf16_t)acc0[4*gr + jj];
            o1[jj] = (bf16_t)acc1[4*gr + jj];
        }
        *(bf16x4*)(OP + prow*DK + gr*8 + hi*4)      = o0;
        *(bf16x4*)(OP + prow*DK + 32 + gr*8 + hi*4) = o1;
    }
    if (hi == 0) {
        float2 ml = {mrun, lsum};
        *(float2*)(ML + prow*2) = ml;
    }
}

// Combine split-KV partials -> CTX (bf16)
__global__ __launch_bounds__(256) void attn_combine_kernel(
        const bf16_t* __restrict__ OP, const float* __restrict__ ML, bf16_t* __restrict__ CTX) {
    int tid = threadIdx.x;
    int r = tid >> 2, dc = (tid & 3) << 4;
    int h = blockIdx.y, b = blockIdx.z;
    int q = blockIdx.x * 64 + r;
    const size_t P = (size_t)BATCH * HEADS * SEQ;
    size_t row0 = ((size_t)b * HEADS + h) * SEQ + q;
    size_t row1 = row0 + P;
    float2 ml0 = *(const float2*)(ML + row0*2);
    float2 ml1 = *(const float2*)(ML + row1*2);
    float M = fmaxf(ml0.x, ml1.x);
    float w0 = exp2f(ml0.x - M), w1 = exp2f(ml1.x - M);
    float inv = 1.0f / (w0*ml0.y + w1*ml1.y);
    w0 *= inv; w1 *= inv;
    const bf16x8* pa = (const bf16x8*)(OP + row0*DK + dc);
    const bf16x8* pb = (const bf16x8*)(OP + row1*DK + dc);
    bf16_t* dst = CTX + ((size_t)b*SEQ + q)*DM + h*DK + dc;
    #pragma unroll
    for (int k = 0; k < 2; k++) {
        bf16x8 av = pa[k], bv = pb[k];
        bf16x8 o;
        #pragma unroll
        for (int i = 0; i < 8; i++)
            o[i] = (bf16_t)((float)av[i]*w0 + (float)bv[i]*w1);
        *(bf16x8*)(dst + k*8) = o;
    }
}

// In-place LayerNorm over rows of 768
__global__ __launch_bounds__(256) void ln_kernel(float* __restrict__ out,
        const float* __restrict__ gamma, const float* __restrict__ beta) {
    int w = threadIdx.x >> 6, u = threadIdx.x & 63;
    size_t row = (size_t)blockIdx.x * 4 + w;
    float x[12];
    float s = 0.f;
    #pragma unroll
    for (int i = 0; i < 12; i++) { x[i] = out[row*DM + i*64 + u]; s += x[i]; }
    #pragma unroll
    for (int d = 1; d < 64; d <<= 1) s += __shfl_xor(s, d);
    float mu = s * (1.0f/768.0f);
    float v = 0.f;
    #pragma unroll
    for (int i = 0; i < 12; i++) { float t = x[i] - mu; v += t*t; }
    #pragma unroll
    for (int d = 1; d < 64; d <<= 1) v += __shfl_xor(v, d);
    float rstd = rsqrtf(v * (1.0f/768.0f) + 1e-5f);
    #pragma unroll
    for (int i = 0; i < 12; i++)
        out[row*DM + i*64 + u] = (x[i] - mu) * rstd * gamma[i*64 + u] + beta[i*64 + u];
}

extern "C" void kernel_launch(void* const* d_in, const int* in_sizes, int n_in,
                              void* d_out, int out_size, void* d_ws, size_t ws_size,
                              hipStream_t stream) {
    const float* Q    = (const float*)d_in[0];
    const float* K    = (const float*)d_in[1];
    const float* V    = (const float*)d_in[2];
    const void*  mask = d_in[3];
    const float* WQ   = (const float*)d_in[4];
    const float* bQ   = (const float*)d_in[5];
    const float* WK   = (const float*)d_in[6];
    const float* bK   = (const float*)d_in[7];
    const float* WV   = (const float*)d_in[8];
    const float* bV   = (const float*)d_in[9];
    const float* Wfc  = (const float*)d_in[10];
    const float* bfc  = (const float*)d_in[11];
    const float* gam  = (const float*)d_in[12];
    const float* bet  = (const float*)d_in[13];
    float* out = (float*)d_out;
    char* ws = (char*)d_ws;

    int* flag            = (int*)(ws + OFF_FLAG);
    unsigned int* maskw  = (unsigned int*)(ws + OFF_MASK);
    bf16_t* WT           = (bf16_t*)(ws + OFF_WT);
    bf16_t* XB           = (bf16_t*)(ws + OFF_XB);
    bf16_t* QP           = (bf16_t*)(ws + OFF_QP);
    bf16_t* KP           = (bf16_t*)(ws + OFF_KP);
    bf16_t* VT           = (bf16_t*)(ws + OFF_VT);
    float*  ML           = (float*)(ws + OFF_ML);
    bf16_t* CTX          = XB;                                    // alias slot 0
    bf16_t* OP           = (bf16_t*)(ws + OFF_XB + SZ_X);        // alias slots 1,2

    detect_mask_kernel<<<1, 64, 0, stream>>>((const unsigned char*)mask, flag);
    pack_mask_kernel<<<2048, 256, 0, stream>>>(mask, flag, maskw);
    xcvt_kernel<<<dim3(3072, 3), 256, 0, stream>>>(Q, K, V, XB);
    wt_cvt_kernel<<<dim3(12, 12, 4), 256, 0, stream>>>(WQ, WK, WV, Wfc, WT);
    proj96_kernel<<<dim3(64, 8, 3), 256, 0, stream>>>(XB, WT, bQ, bK, bV, QP, KP, VT);
    attn_kernel<<<dim3(SEQ/128, HEADS, BATCH*2), 256, 0, stream>>>(QP, KP, VT, maskw, OP, ML);
    attn_combine_kernel<<<dim3(SEQ/64, HEADS, BATCH), 256, 0, stream>>>(OP, ML, CTX);
    out96_kernel<<<dim3(64, 8), 256, 0, stream>>>(CTX, WT + (size_t)3*DM*DM, bfc, Q, out);
    ln_kernel<<<2048, 256, 0, stream>>>(out, gam, bet);
}